// Round 5
// baseline (759.457 us; speedup 1.0000x reference)
//
#include <hip/hip_runtime.h>

// Problem constants (fixed by the reference): B=1
#define S_DIM 128
#define L_DIM 256
#define D_DIM 768
#define H_DIM 12
#define TD    2304            // 3*D
#define NROW  32768           // S*L
#define KDIM  768
#define LN_EPS 1e-5f

typedef unsigned short u16;
typedef unsigned int   u32;
typedef _Float16 f16;
typedef _Float16 f16x8 __attribute__((ext_vector_type(8)));
typedef _Float16 f16x4 __attribute__((ext_vector_type(4)));
typedef float    f32x4 __attribute__((ext_vector_type(4)));

// Workspace layout (bytes), total 224,133,120:
//  region R (151 MB, off 0) is time-multiplexed:
//    row phase : qt f16[H][L][8192] 50.33M | kt same | vt f16[H][8192][256] 50.33M
//                (qt slot is reused as rout_h f16[NROW][D] after row_logits)
//    col phase : p  f16[NROW][TD]  151 MB   (GEMM2 overwrites; qt/kt/vt dead)
#define WS_QT_OFF     0
#define WS_KT_OFF     50331648
#define WS_VT_OFF     100663296
#define WS_P_OFF      0
#define WS_LPART_OFF  150994944
#define WS_PT_OFF     163577856
#define WS_XH_OFF     166723584
#define WS_WRH_OFF    217055232
#define WS_WCH_OFF    220594176

// fp16 staging (NOT bf16): row logits accumulate K=8192 products; bf16 failed
// absmax. fp16 passes at 0.047 with fp16-input MFMA, fp32 accum.
__device__ __forceinline__ void gload_lds16(const void* g, void* l) {
    __builtin_amdgcn_global_load_lds((const __attribute__((address_space(1))) void*)g,
                                     (__attribute__((address_space(3))) void*)l, 16, 0, 0);
}

// ---------------------------------------------------------------------------
// f32 -> f16 convert, 4 elems/thread, grid sized exactly (n % 1024 == 0).
// ---------------------------------------------------------------------------
__global__ __launch_bounds__(256)
void cvt_f32_f16(const float* __restrict__ in, f16* __restrict__ out)
{
    int i = blockIdx.x * 256 + threadIdx.x;
    float4 v = ((const float4*)in)[i];
    f16x4 o; o.x = (f16)v.x; o.y = (f16)v.y; o.z = (f16)v.z; o.w = (f16)v.w;
    ((f16x4*)out)[i] = o;
}

// ---------------------------------------------------------------------------
// MFMA GEMM core (m97 pattern, used by logits/PV): 128x128 tile, BK=32,
// 256 thr = 4 waves (2x2 of 64x64), each wave 4x4 of mfma_f32_16x16x32_f16.
// ---------------------------------------------------------------------------
#define MFMA_PROLOG(KROW)                                                     \
    __shared__ f16 As[128 * 32];                                              \
    __shared__ f16 Bs[128 * 32];                                              \
    const int tid  = threadIdx.x;                                             \
    const int lane = tid & 63;                                                \
    const int w    = tid >> 6;                                                \
    const int wr   = (w >> 1) * 64;                                           \
    const int wc   = (w & 1) * 64;                                            \
    const int lm   = lane & 15;                                               \
    const int q    = lane >> 4;                                               \
    size_t soff[2];                                                           \
    int    ldsc[2];                                                           \
    _Pragma("unroll")                                                         \
    for (int t = 0; t < 2; ++t) {                                             \
        int c  = w * 128 + t * 64 + lane;                                     \
        int m  = c >> 2;                                                      \
        int gj = (c & 3) ^ ((m >> 1) & 3);                                    \
        soff[t] = (size_t)m * (KROW) + gj * 8;                                \
        ldsc[t] = (w * 128 + t * 64) * 8;                                     \
    }                                                                         \
    int chA[4], chB[4];                                                       \
    _Pragma("unroll")                                                         \
    for (int t = 0; t < 4; ++t) {                                             \
        int ma = wr + t * 16 + lm;                                            \
        chA[t] = ma * 4 + (q ^ ((ma >> 1) & 3));                              \
        int mb = wc + t * 16 + lm;                                            \
        chB[t] = mb * 4 + (q ^ ((mb >> 1) & 3));                              \
    }                                                                         \
    f32x4 acc[4][4];                                                          \
    _Pragma("unroll")                                                         \
    for (int i = 0; i < 4; ++i)                                               \
        _Pragma("unroll")                                                     \
        for (int j = 0; j < 4; ++j) acc[i][j] = (f32x4)0.f;

#define MFMA_KLOOP(baseA, baseB, KLEN)                                        \
    for (int k0 = 0; k0 < (KLEN); k0 += 32) {                                 \
        _Pragma("unroll")                                                     \
        for (int t = 0; t < 2; ++t) {                                         \
            gload_lds16((baseA) + soff[t] + k0, &As[ldsc[t]]);                \
            gload_lds16((baseB) + soff[t] + k0, &Bs[ldsc[t]]);                \
        }                                                                     \
        __syncthreads();                                                      \
        f16x8 af[4], bf[4];                                                   \
        _Pragma("unroll")                                                     \
        for (int t = 0; t < 4; ++t) af[t] = *(const f16x8*)&As[chA[t] * 8];   \
        _Pragma("unroll")                                                     \
        for (int t = 0; t < 4; ++t) bf[t] = *(const f16x8*)&Bs[chB[t] * 8];   \
        _Pragma("unroll")                                                     \
        for (int mt = 0; mt < 4; ++mt)                                        \
            _Pragma("unroll")                                                 \
            for (int nt = 0; nt < 4; ++nt)                                    \
                acc[mt][nt] = __builtin_amdgcn_mfma_f32_16x16x32_f16(         \
                    af[mt], bf[nt], acc[mt][nt], 0, 0, 0);                    \
        __syncthreads();                                                      \
    }

// ---------------------------------------------------------------------------
// R5: 128x128-tile GEMM, BK=64, 256 thr = 4 waves (2x2 of 64x64), dbuf LDS
// 64 KB -> 2 blocks/CU (cross-block overlap, the R0 advantage) + counted
// vmcnt(8) (the R3 advantage; never drains to 0 until the last tile).
// Per tile: {stage t+1 into buf^1 (8 gloads) | s_waitcnt vmcnt(8) [t landed,
// t+1's 8 in flight] | s_barrier | compute (32 MFMA) | s_barrier}.
// Epilogue: acc -> swizzled LDS (reusing the staging 64KB) -> fully
// coalesced 128-256B global stores (fixes the 40% WRITE overfetch of the
// scatter epilogue: WRITE_SIZE 210MB for 151MB logical, R3 counters).
// Swizzle: row of 8 16B-chunks, chunk j at j^(row&7), pre-swizzled source,
// XOR on read (0 bank conflicts, proven R1-R4).
// ---------------------------------------------------------------------------
#define R5_WAIT_(N) asm volatile("s_waitcnt vmcnt(" #N ")" ::: "memory")
#define R5_WAIT(N)  R5_WAIT_(N)

#define R5_PROLOG()                                                           \
    __shared__ __align__(16) char SMEM[65536];                                \
    f16* const As0 = (f16*)(SMEM);                                            \
    f16* const Bs0 = (f16*)(SMEM + 16384);                                    \
    f16* const As1 = (f16*)(SMEM + 32768);                                    \
    f16* const Bs1 = (f16*)(SMEM + 49152);                                    \
    const int tid  = threadIdx.x;                                             \
    const int lane = tid & 63;                                                \
    const int w    = tid >> 6;                                                \
    const int wr   = (w >> 1) * 64;                                           \
    const int wc   = (w & 1) * 64;                                            \
    const int lm   = lane & 15;                                               \
    const int q    = lane >> 4;                                               \
    size_t soff[4];                                                           \
    int    ldsb[4];                                                           \
    _Pragma("unroll")                                                         \
    for (int i = 0; i < 4; ++i) {                                             \
        int c = i * 256 + tid;                                                \
        int r = c >> 3;                                                       \
        int j = (c & 7) ^ (r & 7);                                            \
        soff[i] = (size_t)r * KDIM + j * 8;                                   \
        ldsb[i] = (i * 256 + w * 64) * 8;                                     \
    }                                                                         \
    f32x4 acc[4][4];                                                          \
    _Pragma("unroll")                                                         \
    for (int i = 0; i < 4; ++i)                                               \
        _Pragma("unroll")                                                     \
        for (int j = 0; j < 4; ++j) acc[i][j] = (f32x4)0.f;

#define R5_STAGE(Ad, Bd, kk)                                                  \
    _Pragma("unroll")                                                         \
    for (int i = 0; i < 4; ++i)                                               \
        gload_lds16(baseA + soff[i] + (size_t)(kk) * 64, &Ad[ldsb[i]]);       \
    _Pragma("unroll")                                                         \
    for (int i = 0; i < 4; ++i)                                               \
        gload_lds16(baseB + soff[i] + (size_t)(kk) * 64, &Bd[ldsb[i]]);

#define R5_FRAG(buf, row, ks)                                                 \
    (*(const f16x8*)&buf[(size_t)(row) * 64 +                                 \
                         ((((ks) * 4 + q) ^ ((row) & 7)) * 8)])

#define R5_COMPUTE(Ab, Bb)                                                    \
    _Pragma("unroll")                                                         \
    for (int ks = 0; ks < 2; ++ks) {                                          \
        f16x8 af[4], bf[4];                                                   \
        _Pragma("unroll")                                                     \
        for (int mt = 0; mt < 4; ++mt)                                        \
            af[mt] = R5_FRAG(Ab, wr + mt * 16 + lm, ks);                      \
        _Pragma("unroll")                                                     \
        for (int nt = 0; nt < 4; ++nt)                                        \
            bf[nt] = R5_FRAG(Bb, wc + nt * 16 + lm, ks);                      \
        __builtin_amdgcn_s_setprio(1);                                        \
        _Pragma("unroll")                                                     \
        for (int mt = 0; mt < 4; ++mt)                                        \
            _Pragma("unroll")                                                 \
            for (int nt = 0; nt < 4; ++nt)                                    \
                acc[mt][nt] = __builtin_amdgcn_mfma_f32_16x16x32_f16(         \
                    af[mt], bf[nt], acc[mt][nt], 0, 0, 0);                    \
        __builtin_amdgcn_s_setprio(0);                                        \
    }

#define R5_TILE(Ac, Bc, An, Bn, kn, PF, WN)                                   \
    if (PF) { R5_STAGE(An, Bn, kn) }                                          \
    R5_WAIT(WN);                                                              \
    __builtin_amdgcn_s_barrier();                                             \
    __builtin_amdgcn_sched_barrier(0);                                        \
    R5_COMPUTE(Ac, Bc)                                                        \
    __builtin_amdgcn_sched_barrier(0);                                        \
    __builtin_amdgcn_s_barrier();

// KDIM = 768 -> 12 tiles, fully peeled (static buffer names).
#define R5_KLOOP768()                                                         \
    R5_STAGE(As0, Bs0, 0)                                                     \
    R5_TILE(As0, Bs0, As1, Bs1, 1,  1, 8)                                     \
    R5_TILE(As1, Bs1, As0, Bs0, 2,  1, 8)                                     \
    R5_TILE(As0, Bs0, As1, Bs1, 3,  1, 8)                                     \
    R5_TILE(As1, Bs1, As0, Bs0, 4,  1, 8)                                     \
    R5_TILE(As0, Bs0, As1, Bs1, 5,  1, 8)                                     \
    R5_TILE(As1, Bs1, As0, Bs0, 6,  1, 8)                                     \
    R5_TILE(As0, Bs0, As1, Bs1, 7,  1, 8)                                     \
    R5_TILE(As1, Bs1, As0, Bs0, 8,  1, 8)                                     \
    R5_TILE(As0, Bs0, As1, Bs1, 9,  1, 8)                                     \
    R5_TILE(As1, Bs1, As0, Bs0, 10, 1, 8)                                     \
    R5_TILE(As0, Bs0, As1, Bs1, 11, 1, 8)                                     \
    R5_TILE(As1, Bs1, As0, Bs0, 0,  0, 0)

// XCD-aware bijective swizzle: nwg = 18*256 = 4608 = 8*576 (divisible).
#define R5_SWIZZLE()                                                          \
    const int wg   = blockIdx.y * 18 + blockIdx.x;                            \
    const int swz  = (wg & 7) * 576 + (wg >> 3);                              \
    const int row0 = (swz / 18) * 128;                                        \
    const int col0 = (swz % 18) * 128;

// Deposit acc (+bias) into swizzled LDS [128 n][128 col]: 16B chunk c of row
// n stored at chunk c^(n&7). 32 KB, overlays the dead staging buffers.
#define R5_DEPOSIT_ROWMAJOR(EP)                                               \
    _Pragma("unroll")                                                         \
    for (int mt = 0; mt < 4; ++mt)                                            \
        _Pragma("unroll")                                                     \
        for (int nt = 0; nt < 4; ++nt) {                                      \
            const int col = wc + nt * 16 + lm;                                \
            _Pragma("unroll")                                                 \
            for (int r = 0; r < 4; ++r) {                                     \
                const int n = wr + mt * 16 + q * 4 + r;                       \
                EP[n * 128 + (((col >> 3) ^ (n & 7)) << 3) + (col & 7)] =     \
                    (f16)(acc[mt][nt][r] + bv[nt]);                           \
            }                                                                 \
        }                                                                     \
    __syncthreads();

// ---------------------------------------------------------------------------
// GEMM2 (col QKV): C = A*W^T + bias -> p f16 [NROW][TD]. grid (18,256) x256.
// ---------------------------------------------------------------------------
__global__ __launch_bounds__(256, 2)
void mfma_gemm_qkv(const f16* __restrict__ A, const f16* __restrict__ W,
                   const float* __restrict__ bias, f16* __restrict__ C)
{
    R5_SWIZZLE()
    R5_PROLOG()
    const f16* baseA = A + (size_t)row0 * KDIM;
    const f16* baseB = W + (size_t)col0 * KDIM;
    R5_KLOOP768()

    float bv[4];
#pragma unroll
    for (int nt = 0; nt < 4; ++nt) bv[nt] = bias[col0 + wc + nt * 16 + lm];
    f16* const EP = (f16*)SMEM;
    R5_DEPOSIT_ROWMAJOR(EP)

    // drain: 2 threads per n-row, each 64 contiguous cols (128 B stores)
    {
        const int n = tid >> 1, half = tid & 1;
        f16* dst = C + (size_t)(row0 + n) * TD + col0 + half * 64;
#pragma unroll
        for (int c = 0; c < 8; ++c) {
            const int ch = half * 8 + c;
            float4 v4 = *(const float4*)&EP[n * 128 + ((ch ^ (n & 7)) << 3)];
            *(float4*)(dst + c * 8) = v4;
        }
    }
}

// ---------------------------------------------------------------------------
// GEMM1 (row QKV): same core; epilogue routes through LDS for coalescing:
//   q -> qt[h][i][s*64+c], k -> kt[h][j][s*64+c]  (128B contiguous stores)
//   v -> vt[h][s*64+d][j]                          (256B contiguous stores,
//        via transposed LDS deposit [col][n])
// 128-wide col tiles never straddle the 768/1536 q/k/v boundaries.
// ---------------------------------------------------------------------------
__global__ __launch_bounds__(256, 2)
void mfma_gemm_row(const f16* __restrict__ A, const f16* __restrict__ W,
                   const float* __restrict__ bias,
                   f16* __restrict__ qt, f16* __restrict__ kt,
                   f16* __restrict__ vt)
{
    R5_SWIZZLE()
    R5_PROLOG()
    const f16* baseA = A + (size_t)row0 * KDIM;
    const f16* baseB = W + (size_t)col0 * KDIM;
    R5_KLOOP768()

    float bv[4];
#pragma unroll
    for (int nt = 0; nt < 4; ++nt) bv[nt] = bias[col0 + wc + nt * 16 + lm];
    const int s     = row0 >> 8;
    const int ibase = row0 & 255;   // 0 or 128

    if (col0 < 1536) {
        f16* const EP = (f16*)SMEM;
        R5_DEPOSIT_ROWMAJOR(EP)
        // drain: task = (n, hb): 64 cols = one h's c-range, 128B contiguous
        const int n  = tid & 127, hb = tid >> 7;
        const int gcol = ((col0 < 768) ? col0 : col0 - 768) + hb * 64;
        const int h  = gcol >> 6;
        f16* dst = ((col0 < 768) ? qt : kt) +
                   ((((size_t)h * 256 + ibase + n) * 128 + s) << 6);
#pragma unroll
        for (int c = 0; c < 8; ++c) {
            const int ch = hb * 8 + c;
            float4 v4 = *(const float4*)&EP[n * 128 + ((ch ^ (n & 7)) << 3)];
            *(float4*)(dst + c * 8) = v4;
        }
    } else {
        // transposed deposit: EPT[col][n], pitch 136 (2-way bank, free)
        f16* const EPT = (f16*)SMEM;
#pragma unroll
        for (int mt = 0; mt < 4; ++mt)
#pragma unroll
            for (int nt = 0; nt < 4; ++nt) {
                const int lc = wc + nt * 16 + lm;
#pragma unroll
                for (int r = 0; r < 4; ++r) {
                    const int n = wr + mt * 16 + q * 4 + r;
                    EPT[lc * 136 + n] = (f16)(acc[mt][nt][r] + bv[nt]);
                }
            }
        __syncthreads();
        if (tid < 128) {
            const int lc = tid;
            const int vcol = col0 - 1536 + lc;
            const int h = vcol >> 6, d = vcol & 63;
            f16* dst = vt + ((((size_t)h * 128 + s) * 64 + d) << 8) + ibase;
#pragma unroll
            for (int c = 0; c < 16; ++c) {
                float4 v4 = *(const float4*)&EPT[lc * 136 + c * 8];
                *(float4*)(dst + c * 8) = v4;
            }
        }
    }
}

// ---------------------------------------------------------------------------
// Row logits via MFMA: split-K=4 partials. grid (2, 2, 48): z = h*4+sp.
// ---------------------------------------------------------------------------
__global__ __launch_bounds__(256)
void row_logits_mfma(const f16* __restrict__ qt, const f16* __restrict__ kt,
                     float* __restrict__ lpart)
{
    const int i0 = blockIdx.y * 128;
    const int j0 = blockIdx.x * 128;
    const int h  = blockIdx.z >> 2;
    const int sp = blockIdx.z & 3;
    MFMA_PROLOG(8192)
    const f16* baseA = qt + ((size_t)h * 256 + i0) * 8192 + sp * 2048;
    const f16* baseB = kt + ((size_t)h * 256 + j0) * 8192 + sp * 2048;
    MFMA_KLOOP(baseA, baseB, 2048)

    float* outp = lpart + (size_t)(sp * 12 + h) * 65536;
#pragma unroll
    for (int mt = 0; mt < 4; ++mt) {
        int grow = i0 + wr + mt * 16 + q * 4;
#pragma unroll
        for (int nt = 0; nt < 4; ++nt) {
            int gcol = j0 + wc + nt * 16 + lm;
#pragma unroll
            for (int r = 0; r < 4; ++r)
                outp[(size_t)(grow + r) * 256 + gcol] = acc[mt][nt][r];
        }
    }
}

// ---------------------------------------------------------------------------
// softmax over rows of 256, summing 4 split-K partials; probs out f16.
// ---------------------------------------------------------------------------
__global__ __launch_bounds__(256)
void softmax256_4(const float* __restrict__ lpart, f16* __restrict__ pt)
{
    __shared__ float red[256];
    const int t = threadIdx.x;
    const size_t idx = (size_t)blockIdx.x * 256 + t;
    const size_t P = (size_t)12 * 65536;
    float v = lpart[idx] + lpart[idx + P] + lpart[idx + 2*P] + lpart[idx + 3*P];
    red[t] = v; __syncthreads();
    for (int w = 128; w > 0; w >>= 1) { if (t < w) red[t] = fmaxf(red[t], red[t+w]); __syncthreads(); }
    float m = red[0];
    __syncthreads();
    float e = __expf(v - m);
    red[t] = e; __syncthreads();
    for (int w = 128; w > 0; w >>= 1) { if (t < w) red[t] += red[t+w]; __syncthreads(); }
    pt[idx] = (f16)(e / red[0]);
}

// ---------------------------------------------------------------------------
// Row PV via MFMA: per h, out[i,(s,d)] = sum_j pt[h][i][j] * vt[h][(s,d)][j].
// Output f16 (rout_h, in the dead qt slot): halves PV-write + LN1-read HBM.
// ---------------------------------------------------------------------------
__global__ __launch_bounds__(256)
void row_pv_mfma(const f16* __restrict__ pt, const f16* __restrict__ vt,
                 f16* __restrict__ rout)
{
    const int n0t = blockIdx.x * 128;
    const int i0  = blockIdx.y * 128;
    const int h   = blockIdx.z;
    MFMA_PROLOG(256)
    const f16* baseA = pt + (size_t)h * 65536 + (size_t)i0 * 256;
    const f16* baseB = vt + ((size_t)h * 8192 + n0t) * 256;
    MFMA_KLOOP(baseA, baseB, 256)

#pragma unroll
    for (int mt = 0; mt < 4; ++mt) {
        int irow = i0 + wr + mt * 16 + q * 4;
#pragma unroll
        for (int nt = 0; nt < 4; ++nt) {
            int n = n0t + wc + nt * 16 + lm;
            int s = n >> 6, d = n & 63;
#pragma unroll
            for (int r = 0; r < 4; ++r)
                rout[(size_t)(s * 256 + irow + r) * D_DIM + h * 64 + d] =
                    (f16)acc[mt][nt][r];
        }
    }
}

// ---------------------------------------------------------------------------
// out1_h = f16(LN(x16 + r)); both f16 now (x re-read in f32 was 50MB extra;
// f16 rounding of x adds ~5e-4 rel err, margin 2.4x on absmax thr).
// ---------------------------------------------------------------------------
__global__ __launch_bounds__(256)
void add_ln_out16(const f16* __restrict__ x16, const f16* __restrict__ r,
                  const float* __restrict__ g, const float* __restrict__ beta,
                  f16* __restrict__ out16)
{
    __shared__ float red[256];
    const int n = blockIdx.x, t = threadIdx.x;
    const f16* xp = x16 + (size_t)n * D_DIM;
    const f16* rp = r   + (size_t)n * D_DIM;
    float v[3]; float s = 0.f;
#pragma unroll
    for (int e = 0; e < 3; ++e) { v[e] = (float)xp[t + e*256] + (float)rp[t + e*256]; s += v[e]; }
    red[t] = s; __syncthreads();
    for (int w = 128; w > 0; w >>= 1) { if (t < w) red[t] += red[t+w]; __syncthreads(); }
    float mean = red[0] * (1.f/768.f);
    __syncthreads();
    float sq = 0.f;
#pragma unroll
    for (int e = 0; e < 3; ++e) { float d = v[e] - mean; sq += d*d; }
    red[t] = sq; __syncthreads();
    for (int w = 128; w > 0; w >>= 1) { if (t < w) red[t] += red[t+w]; __syncthreads(); }
    float rstd = rsqrtf(red[0] * (1.f/768.f) + LN_EPS);
#pragma unroll
    for (int e = 0; e < 3; ++e) {
        int idx = t + e*256;
        out16[(size_t)n * D_DIM + idx] = (f16)((v[e] - mean) * rstd * g[idx] + beta[idx]);
    }
}

// ---------------------------------------------------------------------------
// out = LN(x16 + r) f32, in place on r. grid NROW, block 256.
// ---------------------------------------------------------------------------
__global__ __launch_bounds__(256)
void add_ln_in16(const f16* __restrict__ x16, float* __restrict__ r,
                 const float* __restrict__ g, const float* __restrict__ beta)
{
    __shared__ float red[256];
    const int n = blockIdx.x, t = threadIdx.x;
    const f16*   xp = x16 + (size_t)n * D_DIM;
    float*       rp = r   + (size_t)n * D_DIM;
    float v[3]; float s = 0.f;
#pragma unroll
    for (int e = 0; e < 3; ++e) { v[e] = (float)xp[t + e*256] + rp[t + e*256]; s += v[e]; }
    red[t] = s; __syncthreads();
    for (int w = 128; w > 0; w >>= 1) { if (t < w) red[t] += red[t+w]; __syncthreads(); }
    float mean = red[0] * (1.f/768.f);
    __syncthreads();
    float sq = 0.f;
#pragma unroll
    for (int e = 0; e < 3; ++e) { float d = v[e] - mean; sq += d*d; }
    red[t] = sq; __syncthreads();
    for (int w = 128; w > 0; w >>= 1) { if (t < w) red[t] += red[t+w]; __syncthreads(); }
    float rstd = rsqrtf(red[0] * (1.f/768.f) + LN_EPS);
#pragma unroll
    for (int e = 0; e < 3; ++e) {
        int idx = t + e*256;
        rp[idx] = (v[e] - mean) * rstd * g[idx] + beta[idx];
    }
}

// ---------------------------------------------------------------------------
// Column attention via MFMA. One block per (l,h): grid (256, 12), 256 thr.
// ---------------------------------------------------------------------------
__global__ __launch_bounds__(256, 3)
void col_attn_mfma(const f16* __restrict__ p, float* __restrict__ cout)
{
    __shared__ char smem[54272];
    f16* Qs = (f16*)smem;             // [128][72]
    f16* Ks = (f16*)(smem + 18432);   // [128][72]
    f16* Ps = (f16*)smem;             // [128][136] overlay (after barrier)
    f16* Vt = (f16*)(smem + 36864);   // [64][136]

    const int tid  = threadIdx.x;
    const int lane = tid & 63;
    const int w    = tid >> 6;
    const int lm   = lane & 15;
    const int q    = lane >> 4;
    const int l = blockIdx.x, h = blockIdx.y;
    const int ib = w * 32;

    // ---- phase 1: stage Q,K row-major; V transposed into Vt[d][j]
    {
        const int r  = tid >> 1;          // s index 0..127
        const int hc = (tid & 1) * 32;    // c half
        const f16* rowp = p + (size_t)(r * 256 + l) * TD + h * 64 + hc;
#pragma unroll
        for (int cc = 0; cc < 4; ++cc)
            *(float4*)&Qs[r * 72 + hc + cc * 8] = *(const float4*)(rowp + cc * 8);
#pragma unroll
        for (int cc = 0; cc < 4; ++cc)
            *(float4*)&Ks[r * 72 + hc + cc * 8] = *(const float4*)(rowp + 768 + cc * 8);
#pragma unroll
        for (int cc = 0; cc < 4; ++cc) {
            union { float4 f; u16 u[8]; } vb;
            vb.f = *(const float4*)(rowp + 1536 + cc * 8);
#pragma unroll
            for (int e = 0; e < 8; ++e) {
                int d = hc + cc * 8 + e;
                ((u16*)Vt)[d * 136 + r] = vb.u[e];
            }
        }
    }
    __syncthreads();

    // ---- phase 2: S = Q K^T (wave tile 32x128: 2 mt x 8 nt x 2 ksteps)
    f32x4 acc[2][8];
#pragma unroll
    for (int mt = 0; mt < 2; ++mt)
#pragma unroll
        for (int nt = 0; nt < 8; ++nt) acc[mt][nt] = (f32x4)0.f;
#pragma unroll
    for (int ks = 0; ks < 2; ++ks) {
        f16x8 af[2];
#pragma unroll
        for (int mt = 0; mt < 2; ++mt)
            af[mt] = *(const f16x8*)&Qs[(ib + mt * 16 + lm) * 72 + ks * 32 + q * 8];
#pragma unroll
        for (int nt = 0; nt < 8; ++nt) {
            f16x8 bf = *(const f16x8*)&Ks[(nt * 16 + lm) * 72 + ks * 32 + q * 8];
#pragma unroll
            for (int mt = 0; mt < 2; ++mt)
                acc[mt][nt] = __builtin_amdgcn_mfma_f32_16x16x32_f16(
                    af[mt], bf, acc[mt][nt], 0, 0, 0);
        }
    }
    __syncthreads();   // all Qs/Ks frag reads done before Ps overlay writes

    // ---- phase 3: softmax over j in C-layout; write exp to Ps (f16)
    float inv_sum[2][4];
#pragma unroll
    for (int mt = 0; mt < 2; ++mt) {
#pragma unroll
        for (int r = 0; r < 4; ++r) {
            float m = acc[mt][0][r];
#pragma unroll
            for (int nt = 1; nt < 8; ++nt) m = fmaxf(m, acc[mt][nt][r]);
#pragma unroll
            for (int d = 1; d < 16; d <<= 1) m = fmaxf(m, __shfl_xor(m, d));
            float s = 0.f;
#pragma unroll
            for (int nt = 0; nt < 8; ++nt) {
                float e = __expf(acc[mt][nt][r] - m);
                acc[mt][nt][r] = e; s += e;
            }
#pragma unroll
            for (int d = 1; d < 16; d <<= 1) s += __shfl_xor(s, d);
            inv_sum[mt][r] = 1.f / s;
        }
        const int irow = ib + mt * 16 + q * 4;
#pragma unroll
        for (int nt = 0; nt < 8; ++nt) {
            const int jj = nt * 16 + lm;
#pragma unroll
            for (int r = 0; r < 4; ++r)
                Ps[(irow + r) * 136 + jj] = (f16)acc[mt][nt][r];
        }
    }
    __syncthreads();

    // ---- phase 4: O = P~ V (wave tile 32x64: 2 mt x 4 nt x 4 ksteps)
    f32x4 acc2[2][4];
#pragma unroll
    for (int mt = 0; mt < 2; ++mt)
#pragma unroll
        for (int nt = 0; nt < 4; ++nt) acc2[mt][nt] = (f32x4)0.f;
#pragma unroll
    for (int ks = 0; ks < 4; ++ks) {
        f16x8 pf[2];
#pragma unroll
        for (int mt = 0; mt < 2; ++mt)
            pf[mt] = *(const f16x8*)&Ps[(ib + mt * 16 + lm) * 136 + ks * 32 + q * 8];
#pragma unroll
        for (int nt = 0; nt < 4; ++nt) {
            f16x8 vf = *(const f16x8*)&Vt[(nt * 16 + lm) * 136 + ks * 32 + q * 8];
#pragma unroll
            for (int mt = 0; mt < 2; ++mt)
                acc2[mt][nt] = __builtin_amdgcn_mfma_f32_16x16x32_f16(
                    pf[mt], vf, acc2[mt][nt], 0, 0, 0);
        }
    }

    // ---- epilogue: apply deferred 1/sum, write f32
#pragma unroll
    for (int mt = 0; mt < 2; ++mt) {
        const int irow = ib + mt * 16 + q * 4;
#pragma unroll
        for (int nt = 0; nt < 4; ++nt) {
            const int d = nt * 16 + lm;
#pragma unroll
            for (int r = 0; r < 4; ++r)
                cout[(size_t)((irow + r) * 256 + l) * D_DIM + h * 64 + d] =
                    acc2[mt][nt][r] * inv_sum[mt][r];
        }
    }
}

// ---------------------------------------------------------------------------
extern "C" void kernel_launch(void* const* d_in, const int* in_sizes, int n_in,
                              void* d_out, int out_size, void* d_ws, size_t ws_size,
                              hipStream_t stream)
{
    const float* x     = (const float*)d_in[0];
    const float* w_row = (const float*)d_in[1];
    const float* b_row = (const float*)d_in[2];
    const float* w_col = (const float*)d_in[3];
    const float* b_col = (const float*)d_in[4];
    const float* g1    = (const float*)d_in[5];
    const float* be1   = (const float*)d_in[6];
    const float* g2    = (const float*)d_in[7];
    const float* be2   = (const float*)d_in[8];
    float* out = (float*)d_out;

    char* ws = (char*)d_ws;
    f16*   qt     = (f16*)(ws + WS_QT_OFF);
    f16*   kt     = (f16*)(ws + WS_KT_OFF);
    f16*   vt     = (f16*)(ws + WS_VT_OFF);
    f16*   p      = (f16*)(ws + WS_P_OFF);      // col phase, aliases qt/kt/vt
    float* lpart  = (float*)(ws + WS_LPART_OFF);
    f16*   pt     = (f16*)(ws + WS_PT_OFF);
    f16*   xh     = (f16*)(ws + WS_XH_OFF);     // also out1_h after step 5
    f16*   wrh    = (f16*)(ws + WS_WRH_OFF);
    f16*   wch    = (f16*)(ws + WS_WCH_OFF);
    f16*   rout_h = qt;                          // qt dead after row_logits

    // 0) f32 -> f16 converts
    cvt_f32_f16<<<NROW * D_DIM / 1024, 256, 0, stream>>>(x, xh);
    cvt_f32_f16<<<TD * D_DIM / 1024, 256, 0, stream>>>(w_row, wrh);
    cvt_f32_f16<<<TD * D_DIM / 1024, 256, 0, stream>>>(w_col, wch);
    // 1) row QKV projection (128x128 BK=64 counted-vmcnt, 2 blk/CU)
    mfma_gemm_row<<<dim3(18, 256), 256, 0, stream>>>(xh, wrh, b_row, qt, kt, vt);
    // 2) tied row logits (MFMA, split-K=4)
    row_logits_mfma<<<dim3(2, 2, 48), 256, 0, stream>>>(qt, kt, lpart);
    // 3) softmax over j (sums 4 partials) -> f16 probs
    softmax256_4<<<H_DIM * L_DIM, 256, 0, stream>>>(lpart, pt);
    // 4) row PV (MFMA) -> rout_h f16 (qt slot; qt dead after step 2)
    row_pv_mfma<<<dim3(64, 2, H_DIM), 256, 0, stream>>>(pt, vt, rout_h);
    // 5) out1_h = f16(LN(xh + row_out))  (xh overwritten as out1_h, row-local)
    add_ln_out16<<<NROW, 256, 0, stream>>>(xh, rout_h, g1, be1, xh);
    // 6) col QKV projection (same R5 GEMM) -> p (overwrites qt/kt/vt)
    mfma_gemm_qkv<<<dim3(18, 256), 256, 0, stream>>>(xh, wch, b_col, p);
    // 7) column attention (MFMA) -> d_out (scratch)
    col_attn_mfma<<<dim3(L_DIM, H_DIM), 256, 0, stream>>>(p, out);
    // 8) out = LN(out1_h + col_out), in place on d_out
    add_ln_in16<<<NROW, 256, 0, stream>>>(xh, out, g2, be2);
}

// Round 6
// 688.933 us; speedup vs baseline: 1.1024x; 1.1024x over previous
//
#include <hip/hip_runtime.h>

// Problem constants (fixed by the reference): B=1
#define S_DIM 128
#define L_DIM 256
#define D_DIM 768
#define H_DIM 12
#define TD    2304            // 3*D
#define NROW  32768           // S*L
#define KDIM  768
#define LN_EPS 1e-5f

typedef unsigned short u16;
typedef unsigned int   u32;
typedef _Float16 f16;
typedef _Float16 f16x8 __attribute__((ext_vector_type(8)));
typedef _Float16 f16x4 __attribute__((ext_vector_type(4)));
typedef float    f32x4 __attribute__((ext_vector_type(4)));

// Workspace layout (bytes), total 235,143,168 (< 255 MB proven):
//  region R (151 MB, off 0) is time-multiplexed:
//    row phase : qt f16[H][L][8192] 50.33M | kt same | vt f16[H][8192][256] 50.33M
//                (qt slot reused as rout_h f16[NROW][D] after row_logits)
//    col phase : p  f16[NROW][TD]  151 MB   (GEMM2 overwrites; qt/kt/vt dead)
//  lpart  : f32 [8][H][L][L]  25,165,824   (split-K=8 partials for row logits)
//  pt     : f16 [H][L][L]      1,572,864
//  xh/u1h : f16 [NROW][D]     50,331,648
//  wr_h   : f16 [TD][D]        3,538,944
//  wc_h   : f16 [TD][D]        3,538,944
#define WS_QT_OFF     0
#define WS_KT_OFF     50331648
#define WS_VT_OFF     100663296
#define WS_P_OFF      0
#define WS_LPART_OFF  150994944
#define WS_PT_OFF     176160768
#define WS_XH_OFF     177733632
#define WS_WRH_OFF    228065280
#define WS_WCH_OFF    231604224

// fp16 staging (NOT bf16): row logits accumulate K=8192 products; bf16 failed
// absmax. fp16 passes at 0.047 with fp16-input MFMA, fp32 accum.
__device__ __forceinline__ void gload_lds16(const void* g, void* l) {
    __builtin_amdgcn_global_load_lds((const __attribute__((address_space(1))) void*)g,
                                     (__attribute__((address_space(3))) void*)l, 16, 0, 0);
}

// ---------------------------------------------------------------------------
// f32 -> f16 convert, 4 elems/thread, grid sized exactly (n % 1024 == 0).
// ---------------------------------------------------------------------------
__global__ __launch_bounds__(256)
void cvt_f32_f16(const float* __restrict__ in, f16* __restrict__ out)
{
    int i = blockIdx.x * 256 + threadIdx.x;
    float4 v = ((const float4*)in)[i];
    f16x4 o; o.x = (f16)v.x; o.y = (f16)v.y; o.z = (f16)v.z; o.w = (f16)v.w;
    ((f16x4*)out)[i] = o;
}

// ---------------------------------------------------------------------------
// MFMA GEMM core (m97 pattern, used by logits/PV): 128x128 tile, BK=32,
// 256 thr = 4 waves (2x2 of 64x64), each wave 4x4 of mfma_f32_16x16x32_f16.
// ---------------------------------------------------------------------------
#define MFMA_PROLOG(KROW)                                                     \
    __shared__ f16 As[128 * 32];                                              \
    __shared__ f16 Bs[128 * 32];                                              \
    const int tid  = threadIdx.x;                                             \
    const int lane = tid & 63;                                                \
    const int w    = tid >> 6;                                                \
    const int wr   = (w >> 1) * 64;                                           \
    const int wc   = (w & 1) * 64;                                            \
    const int lm   = lane & 15;                                               \
    const int q    = lane >> 4;                                               \
    size_t soff[2];                                                           \
    int    ldsc[2];                                                           \
    _Pragma("unroll")                                                         \
    for (int t = 0; t < 2; ++t) {                                             \
        int c  = w * 128 + t * 64 + lane;                                     \
        int m  = c >> 2;                                                      \
        int gj = (c & 3) ^ ((m >> 1) & 3);                                    \
        soff[t] = (size_t)m * (KROW) + gj * 8;                                \
        ldsc[t] = (w * 128 + t * 64) * 8;                                     \
    }                                                                         \
    int chA[4], chB[4];                                                       \
    _Pragma("unroll")                                                         \
    for (int t = 0; t < 4; ++t) {                                             \
        int ma = wr + t * 16 + lm;                                            \
        chA[t] = ma * 4 + (q ^ ((ma >> 1) & 3));                              \
        int mb = wc + t * 16 + lm;                                            \
        chB[t] = mb * 4 + (q ^ ((mb >> 1) & 3));                              \
    }                                                                         \
    f32x4 acc[4][4];                                                          \
    _Pragma("unroll")                                                         \
    for (int i = 0; i < 4; ++i)                                               \
        _Pragma("unroll")                                                     \
        for (int j = 0; j < 4; ++j) acc[i][j] = (f32x4)0.f;

#define MFMA_KLOOP(baseA, baseB, KLEN)                                        \
    for (int k0 = 0; k0 < (KLEN); k0 += 32) {                                 \
        _Pragma("unroll")                                                     \
        for (int t = 0; t < 2; ++t) {                                         \
            gload_lds16((baseA) + soff[t] + k0, &As[ldsc[t]]);                \
            gload_lds16((baseB) + soff[t] + k0, &Bs[ldsc[t]]);                \
        }                                                                     \
        __syncthreads();                                                      \
        f16x8 af[4], bf[4];                                                   \
        _Pragma("unroll")                                                     \
        for (int t = 0; t < 4; ++t) af[t] = *(const f16x8*)&As[chA[t] * 8];   \
        _Pragma("unroll")                                                     \
        for (int t = 0; t < 4; ++t) bf[t] = *(const f16x8*)&Bs[chB[t] * 8];   \
        _Pragma("unroll")                                                     \
        for (int mt = 0; mt < 4; ++mt)                                        \
            _Pragma("unroll")                                                 \
            for (int nt = 0; nt < 4; ++nt)                                    \
                acc[mt][nt] = __builtin_amdgcn_mfma_f32_16x16x32_f16(         \
                    af[mt], bf[nt], acc[mt][nt], 0, 0, 0);                    \
        __syncthreads();                                                      \
    }

// ---------------------------------------------------------------------------
// 256x192-tile GEMM core with counted-vmcnt ring (best measured: R3, 172us):
// BK=64, 512 thr = 8 waves (4M x 2N), wave tile 64x96 = 4x6 fragments.
// LDS: A ring-3 (3 x 32 KB) + B ring-2 (2 x 24 KB) = 144 KB.
// Per tile t: s_waitcnt vmcnt(4), raw s_barrier + sched_barrier; then stage
// B(t+1), A(t+2); then frags + 48 MFMA. Never drains vmcnt to 0 in loop.
// Swizzle: chunk j at j^(row&7), pre-swizzled source, XOR on read
// (0 bank conflicts, proven).
// ---------------------------------------------------------------------------
#define R3_WAIT_(N) asm volatile("s_waitcnt vmcnt(" #N ")" ::: "memory")
#define R3_WAIT(N)  R3_WAIT_(N)

#define R3_PROLOG()                                                           \
    __shared__ f16 As0[256 * 64];                                             \
    __shared__ f16 As1[256 * 64];                                             \
    __shared__ f16 As2[256 * 64];                                             \
    __shared__ f16 Bs0[192 * 64];                                             \
    __shared__ f16 Bs1[192 * 64];                                             \
    const int tid  = threadIdx.x;                                             \
    const int lane = tid & 63;                                                \
    const int w    = tid >> 6;                                                \
    const int wr   = (w >> 1) * 64;                                           \
    const int wc   = (w & 1) * 96;                                            \
    const int lm   = lane & 15;                                               \
    const int q    = lane >> 4;                                               \
    size_t soffA[4];                                                          \
    _Pragma("unroll")                                                         \
    for (int i = 0; i < 4; ++i) {                                             \
        int c = i * 512 + tid;                                                \
        int r = c >> 3;                                                       \
        int j = (c & 7) ^ (r & 7);                                            \
        soffA[i] = (size_t)r * KDIM + j * 8;                                  \
    }                                                                         \
    size_t soffB[3];                                                          \
    _Pragma("unroll")                                                         \
    for (int i = 0; i < 3; ++i) {                                             \
        int c = i * 512 + tid;                                                \
        int r = c >> 3;                                                       \
        int j = (c & 7) ^ (r & 7);                                            \
        soffB[i] = (size_t)r * KDIM + j * 8;                                  \
    }                                                                         \
    f32x4 acc[4][6];                                                          \
    _Pragma("unroll")                                                         \
    for (int i = 0; i < 4; ++i)                                               \
        _Pragma("unroll")                                                     \
        for (int j = 0; j < 6; ++j) acc[i][j] = (f32x4)0.f;

#define R3_STAGE_A(Ad, kk)                                                    \
    _Pragma("unroll")                                                         \
    for (int i = 0; i < 4; ++i)                                               \
        gload_lds16(baseA + soffA[i] + (size_t)(kk) * 64,                     \
                    &Ad[(i * 512 + w * 64) * 8]);

#define R3_STAGE_B(Bd, kk)                                                    \
    _Pragma("unroll")                                                         \
    for (int i = 0; i < 3; ++i)                                               \
        gload_lds16(baseB + soffB[i] + (size_t)(kk) * 64,                     \
                    &Bd[(i * 512 + w * 64) * 8]);

#define R3_FRAG(buf, row, ks)                                                 \
    (*(const f16x8*)&buf[(size_t)(row) * 64 +                                 \
                         ((((ks) * 4 + q) ^ ((row) & 7)) * 8)])

#define R3_COMPUTE(Ab, Bb)                                                    \
    _Pragma("unroll")                                                         \
    for (int ks = 0; ks < 2; ++ks) {                                          \
        f16x8 af[4], bf[6];                                                   \
        _Pragma("unroll")                                                     \
        for (int mt = 0; mt < 4; ++mt)                                        \
            af[mt] = R3_FRAG(Ab, wr + mt * 16 + lm, ks);                      \
        _Pragma("unroll")                                                     \
        for (int nt = 0; nt < 6; ++nt)                                        \
            bf[nt] = R3_FRAG(Bb, wc + nt * 16 + lm, ks);                      \
        __builtin_amdgcn_s_setprio(1);                                        \
        _Pragma("unroll")                                                     \
        for (int mt = 0; mt < 4; ++mt)                                        \
            _Pragma("unroll")                                                 \
            for (int nt = 0; nt < 6; ++nt)                                    \
                acc[mt][nt] = __builtin_amdgcn_mfma_f32_16x16x32_f16(         \
                    af[mt], bf[nt], acc[mt][nt], 0, 0, 0);                    \
        __builtin_amdgcn_s_setprio(0);                                        \
    }

#define R3_TILE(Ab, Bb, SB, Bn, kb, SA, An, ka, WN)                           \
    R3_WAIT(WN);                                                              \
    __builtin_amdgcn_s_barrier();                                             \
    __builtin_amdgcn_sched_barrier(0);                                        \
    if (SB) { R3_STAGE_B(Bn, kb) }                                            \
    if (SA) { R3_STAGE_A(An, ka) }                                            \
    R3_COMPUTE(Ab, Bb)

// KDIM=768 -> 12 tiles, fully peeled. A buf = t%3, B buf = t%2.
#define R3_KLOOP768()                                                         \
    R3_STAGE_A(As0, 0)                                                        \
    R3_STAGE_B(Bs0, 0)                                                        \
    R3_STAGE_A(As1, 1)                                                        \
    R3_TILE(As0, Bs0, 1, Bs1, 1,  1, As2, 2,  4)                              \
    R3_TILE(As1, Bs1, 1, Bs0, 2,  1, As0, 3,  4)                              \
    R3_TILE(As2, Bs0, 1, Bs1, 3,  1, As1, 4,  4)                              \
    R3_TILE(As0, Bs1, 1, Bs0, 4,  1, As2, 5,  4)                              \
    R3_TILE(As1, Bs0, 1, Bs1, 5,  1, As0, 6,  4)                              \
    R3_TILE(As2, Bs1, 1, Bs0, 6,  1, As1, 7,  4)                              \
    R3_TILE(As0, Bs0, 1, Bs1, 7,  1, As2, 8,  4)                              \
    R3_TILE(As1, Bs1, 1, Bs0, 8,  1, As0, 9,  4)                              \
    R3_TILE(As2, Bs0, 1, Bs1, 9,  1, As1, 10, 4)                              \
    R3_TILE(As0, Bs1, 1, Bs0, 10, 1, As2, 11, 4)                              \
    R3_TILE(As1, Bs0, 1, Bs1, 11, 0, As0, 0,  4)                              \
    R3_TILE(As2, Bs1, 0, Bs0, 0,  0, As0, 0,  0)

// XCD-aware bijective swizzle: nwg = 12*128 = 1536 = 8*192 (divisible).
#define R3_SWIZZLE()                                                          \
    const int wg   = blockIdx.y * 12 + blockIdx.x;                            \
    const int swz  = (wg & 7) * 192 + (wg >> 3);                              \
    const int row0 = (swz / 12) * 256;                                        \
    const int col0 = (swz % 12) * 192;

// ---------------------------------------------------------------------------
// GEMM2 (col QKV): C = A*W^T + bias -> p f16 [NROW][TD]. grid (12,128) x512.
// ---------------------------------------------------------------------------
__global__ __launch_bounds__(512, 2)
void mfma_gemm_qkv(const f16* __restrict__ A, const f16* __restrict__ W,
                   const float* __restrict__ bias, f16* __restrict__ C)
{
    R3_SWIZZLE()
    R3_PROLOG()
    const f16* baseA = A + (size_t)row0 * KDIM;
    const f16* baseB = W + (size_t)col0 * KDIM;
    R3_KLOOP768()

    // C/D layout: col=lane&15, row=quad*4+reg
    float bv[6];
#pragma unroll
    for (int nt = 0; nt < 6; ++nt) bv[nt] = bias[col0 + wc + nt * 16 + lm];
#pragma unroll
    for (int mt = 0; mt < 4; ++mt) {
        int grow = row0 + wr + mt * 16 + q * 4;
#pragma unroll
        for (int nt = 0; nt < 6; ++nt) {
            int gcol = col0 + wc + nt * 16 + lm;
#pragma unroll
            for (int r = 0; r < 4; ++r)
                C[(size_t)(grow + r) * TD + gcol] = (f16)(acc[mt][nt][r] + bv[nt]);
        }
    }
}

// ---------------------------------------------------------------------------
// GEMM1 (row QKV): same core but scatter epilogue:
//   q -> qt[h][i][s*64+c], k -> kt[h][j][s*64+c], v -> vt[h][s*64+d][j].
// col0 tiles (192-wide) never straddle the 768/1536 q/k/v boundaries.
// (Scatter epilogue retained: R5's LDS-coalesced drain was WORSE -- per-lane
//  contiguity is cross-lane stride 16KB; WRITE_SIZE 210->315MB, +786K bank
//  conflicts. Lanes lm=0..15 writing 32B-consecutive is the better layout.)
// ---------------------------------------------------------------------------
__global__ __launch_bounds__(512, 2)
void mfma_gemm_row(const f16* __restrict__ A, const f16* __restrict__ W,
                   const float* __restrict__ bias,
                   f16* __restrict__ qt, f16* __restrict__ kt,
                   f16* __restrict__ vt)
{
    R3_SWIZZLE()
    R3_PROLOG()
    const f16* baseA = A + (size_t)row0 * KDIM;
    const f16* baseB = W + (size_t)col0 * KDIM;
    R3_KLOOP768()

    if (col0 < 1536) {
        f16* dst = (col0 < 768) ? qt : kt;
        const int cbase = (col0 < 768) ? col0 : col0 - 768;
#pragma unroll
        for (int nt = 0; nt < 6; ++nt) {
            int gcol = cbase + wc + nt * 16 + lm;
            int h = gcol >> 6, c = gcol & 63;
            float b = bias[col0 + wc + nt * 16 + lm];
#pragma unroll
            for (int mt = 0; mt < 4; ++mt) {
                int n0 = row0 + wr + mt * 16 + q * 4;
#pragma unroll
                for (int r = 0; r < 4; ++r) {
                    int n = n0 + r;
                    int s = n >> 8, ii = n & 255;
                    dst[(((size_t)h * 256 + ii) * 128 + s) * 64 + c] =
                        (f16)(acc[mt][nt][r] + b);
                }
            }
        }
    } else {
#pragma unroll
        for (int nt = 0; nt < 6; ++nt) {
            int gcol = col0 + wc + nt * 16 + lm;
            int vcol = gcol - 1536;
            int h = vcol >> 6, d = vcol & 63;
            float b = bias[gcol];
#pragma unroll
            for (int mt = 0; mt < 4; ++mt) {
                int n0 = row0 + wr + mt * 16 + q * 4;
                int s = n0 >> 8, j0 = n0 & 255;   // r stays within one s
                f16x4 pack;
#pragma unroll
                for (int r = 0; r < 4; ++r) pack[r] = (f16)(acc[mt][nt][r] + b);
                *(f16x4*)&vt[((((size_t)h * 128 + s) * 64 + d) << 8) + j0] = pack;
            }
        }
    }
}

// ---------------------------------------------------------------------------
// Row logits via MFMA: split-K=8 partials (was 4: 192 blocks < 256 CUs was
// latency-bound at <1 block/CU). grid (2, 2, 96): z = h*8+sp -> 384 blocks,
// K=1024 each (32 BK=32 iters). lpart 8 partials, 25 MB.
// ---------------------------------------------------------------------------
__global__ __launch_bounds__(256)
void row_logits_mfma(const f16* __restrict__ qt, const f16* __restrict__ kt,
                     float* __restrict__ lpart)
{
    const int i0 = blockIdx.y * 128;
    const int j0 = blockIdx.x * 128;
    const int h  = blockIdx.z >> 3;
    const int sp = blockIdx.z & 7;
    MFMA_PROLOG(8192)
    const f16* baseA = qt + ((size_t)h * 256 + i0) * 8192 + sp * 1024;
    const f16* baseB = kt + ((size_t)h * 256 + j0) * 8192 + sp * 1024;
    MFMA_KLOOP(baseA, baseB, 1024)

    float* outp = lpart + (size_t)(sp * 12 + h) * 65536;
#pragma unroll
    for (int mt = 0; mt < 4; ++mt) {
        int grow = i0 + wr + mt * 16 + q * 4;
#pragma unroll
        for (int nt = 0; nt < 4; ++nt) {
            int gcol = j0 + wc + nt * 16 + lm;
#pragma unroll
            for (int r = 0; r < 4; ++r)
                outp[(size_t)(grow + r) * 256 + gcol] = acc[mt][nt][r];
        }
    }
}

// ---------------------------------------------------------------------------
// softmax over rows of 256, summing 8 split-K partials; probs out f16.
// ---------------------------------------------------------------------------
__global__ __launch_bounds__(256)
void softmax256_8(const float* __restrict__ lpart, f16* __restrict__ pt)
{
    __shared__ float red[256];
    const int t = threadIdx.x;
    const size_t idx = (size_t)blockIdx.x * 256 + t;
    const size_t P = (size_t)12 * 65536;
    float v = 0.f;
#pragma unroll
    for (int p8 = 0; p8 < 8; ++p8) v += lpart[idx + p8 * P];
    red[t] = v; __syncthreads();
    for (int w = 128; w > 0; w >>= 1) { if (t < w) red[t] = fmaxf(red[t], red[t+w]); __syncthreads(); }
    float m = red[0];
    __syncthreads();
    float e = __expf(v - m);
    red[t] = e; __syncthreads();
    for (int w = 128; w > 0; w >>= 1) { if (t < w) red[t] += red[t+w]; __syncthreads(); }
    pt[idx] = (f16)(e / red[0]);
}

// ---------------------------------------------------------------------------
// Row PV via MFMA: per h, out[i,(s,d)] = sum_j pt[h][i][j] * vt[h][(s,d)][j].
// Output f16 (rout_h, in the dead qt slot): halves PV-write + LN1-read HBM.
// ---------------------------------------------------------------------------
__global__ __launch_bounds__(256)
void row_pv_mfma(const f16* __restrict__ pt, const f16* __restrict__ vt,
                 f16* __restrict__ rout)
{
    const int n0t = blockIdx.x * 128;
    const int i0  = blockIdx.y * 128;
    const int h   = blockIdx.z;
    MFMA_PROLOG(256)
    const f16* baseA = pt + (size_t)h * 65536 + (size_t)i0 * 256;
    const f16* baseB = vt + ((size_t)h * 8192 + n0t) * 256;
    MFMA_KLOOP(baseA, baseB, 256)

#pragma unroll
    for (int mt = 0; mt < 4; ++mt) {
        int irow = i0 + wr + mt * 16 + q * 4;
#pragma unroll
        for (int nt = 0; nt < 4; ++nt) {
            int n = n0t + wc + nt * 16 + lm;
            int s = n >> 6, d = n & 63;
#pragma unroll
            for (int r = 0; r < 4; ++r)
                rout[(size_t)(s * 256 + irow + r) * D_DIM + h * 64 + d] =
                    (f16)acc[mt][nt][r];
        }
    }
}

// ---------------------------------------------------------------------------
// out1_h = f16(LN(x16 + r)); both f16 (proven R5: absmax unchanged 0.0469).
// ---------------------------------------------------------------------------
__global__ __launch_bounds__(256)
void add_ln_out16(const f16* __restrict__ x16, const f16* __restrict__ r,
                  const float* __restrict__ g, const float* __restrict__ beta,
                  f16* __restrict__ out16)
{
    __shared__ float red[256];
    const int n = blockIdx.x, t = threadIdx.x;
    const f16* xp = x16 + (size_t)n * D_DIM;
    const f16* rp = r   + (size_t)n * D_DIM;
    float v[3]; float s = 0.f;
#pragma unroll
    for (int e = 0; e < 3; ++e) { v[e] = (float)xp[t + e*256] + (float)rp[t + e*256]; s += v[e]; }
    red[t] = s; __syncthreads();
    for (int w = 128; w > 0; w >>= 1) { if (t < w) red[t] += red[t+w]; __syncthreads(); }
    float mean = red[0] * (1.f/768.f);
    __syncthreads();
    float sq = 0.f;
#pragma unroll
    for (int e = 0; e < 3; ++e) { float d = v[e] - mean; sq += d*d; }
    red[t] = sq; __syncthreads();
    for (int w = 128; w > 0; w >>= 1) { if (t < w) red[t] += red[t+w]; __syncthreads(); }
    float rstd = rsqrtf(red[0] * (1.f/768.f) + LN_EPS);
#pragma unroll
    for (int e = 0; e < 3; ++e) {
        int idx = t + e*256;
        out16[(size_t)n * D_DIM + idx] = (f16)((v[e] - mean) * rstd * g[idx] + beta[idx]);
    }
}

// ---------------------------------------------------------------------------
// out = LN(x16 + r) f32, in place on r. grid NROW, block 256.
// ---------------------------------------------------------------------------
__global__ __launch_bounds__(256)
void add_ln_in16(const f16* __restrict__ x16, float* __restrict__ r,
                 const float* __restrict__ g, const float* __restrict__ beta)
{
    __shared__ float red[256];
    const int n = blockIdx.x, t = threadIdx.x;
    const f16*   xp = x16 + (size_t)n * D_DIM;
    float*       rp = r   + (size_t)n * D_DIM;
    float v[3]; float s = 0.f;
#pragma unroll
    for (int e = 0; e < 3; ++e) { v[e] = (float)xp[t + e*256] + rp[t + e*256]; s += v[e]; }
    red[t] = s; __syncthreads();
    for (int w = 128; w > 0; w >>= 1) { if (t < w) red[t] += red[t+w]; __syncthreads(); }
    float mean = red[0] * (1.f/768.f);
    __syncthreads();
    float sq = 0.f;
#pragma unroll
    for (int e = 0; e < 3; ++e) { float d = v[e] - mean; sq += d*d; }
    red[t] = sq; __syncthreads();
    for (int w = 128; w > 0; w >>= 1) { if (t < w) red[t] += red[t+w]; __syncthreads(); }
    float rstd = rsqrtf(red[0] * (1.f/768.f) + LN_EPS);
#pragma unroll
    for (int e = 0; e < 3; ++e) {
        int idx = t + e*256;
        rp[idx] = (v[e] - mean) * rstd * g[idx] + beta[idx];
    }
}

// ---------------------------------------------------------------------------
// Column attention via MFMA. One block per (l,h): grid (256, 12), 256 thr.
// ---------------------------------------------------------------------------
__global__ __launch_bounds__(256, 3)
void col_attn_mfma(const f16* __restrict__ p, float* __restrict__ cout)
{
    __shared__ char smem[54272];
    f16* Qs = (f16*)smem;             // [128][72]
    f16* Ks = (f16*)(smem + 18432);   // [128][72]
    f16* Ps = (f16*)smem;             // [128][136] overlay (after barrier)
    f16* Vt = (f16*)(smem + 36864);   // [64][136]

    const int tid  = threadIdx.x;
    const int lane = tid & 63;
    const int w    = tid >> 6;
    const int lm   = lane & 15;
    const int q    = lane >> 4;
    const int l = blockIdx.x, h = blockIdx.y;
    const int ib = w * 32;

    // ---- phase 1: stage Q,K row-major; V transposed into Vt[d][j]
    {
        const int r  = tid >> 1;          // s index 0..127
        const int hc = (tid & 1) * 32;    // c half
        const f16* rowp = p + (size_t)(r * 256 + l) * TD + h * 64 + hc;
#pragma unroll
        for (int cc = 0; cc < 4; ++cc)
            *(float4*)&Qs[r * 72 + hc + cc * 8] = *(const float4*)(rowp + cc * 8);
#pragma unroll
        for (int cc = 0; cc < 4; ++cc)
            *(float4*)&Ks[r * 72 + hc + cc * 8] = *(const float4*)(rowp + 768 + cc * 8);
#pragma unroll
        for (int cc = 0; cc < 4; ++cc) {
            union { float4 f; u16 u[8]; } vb;
            vb.f = *(const float4*)(rowp + 1536 + cc * 8);
#pragma unroll
            for (int e = 0; e < 8; ++e) {
                int d = hc + cc * 8 + e;
                ((u16*)Vt)[d * 136 + r] = vb.u[e];
            }
        }
    }
    __syncthreads();

    // ---- phase 2: S = Q K^T (wave tile 32x128: 2 mt x 8 nt x 2 ksteps)
    f32x4 acc[2][8];
#pragma unroll
    for (int mt = 0; mt < 2; ++mt)
#pragma unroll
        for (int nt = 0; nt < 8; ++nt) acc[mt][nt] = (f32x4)0.f;
#pragma unroll
    for (int ks = 0; ks < 2; ++ks) {
        f16x8 af[2];
#pragma unroll
        for (int mt = 0; mt < 2; ++mt)
            af[mt] = *(const f16x8*)&Qs[(ib + mt * 16 + lm) * 72 + ks * 32 + q * 8];
#pragma unroll
        for (int nt = 0; nt < 8; ++nt) {
            f16x8 bf = *(const f16x8*)&Ks[(nt * 16 + lm) * 72 + ks * 32 + q * 8];
#pragma unroll
            for (int mt = 0; mt < 2; ++mt)
                acc[mt][nt] = __builtin_amdgcn_mfma_f32_16x16x32_f16(
                    af[mt], bf, acc[mt][nt], 0, 0, 0);
        }
    }
    __syncthreads();   // all Qs/Ks frag reads done before Ps overlay writes

    // ---- phase 3: softmax over j in C-layout; write exp to Ps (f16)
    float inv_sum[2][4];
#pragma unroll
    for (int mt = 0; mt < 2; ++mt) {
#pragma unroll
        for (int r = 0; r < 4; ++r) {
            float m = acc[mt][0][r];
#pragma unroll
            for (int nt = 1; nt < 8; ++nt) m = fmaxf(m, acc[mt][nt][r]);
#pragma unroll
            for (int d = 1; d < 16; d <<= 1) m = fmaxf(m, __shfl_xor(m, d));
            float s = 0.f;
#pragma unroll
            for (int nt = 0; nt < 8; ++nt) {
                float e = __expf(acc[mt][nt][r] - m);
                acc[mt][nt][r] = e; s += e;
            }
#pragma unroll
            for (int d = 1; d < 16; d <<= 1) s += __shfl_xor(s, d);
            inv_sum[mt][r] = 1.f / s;
        }
        const int irow = ib + mt * 16 + q * 4;
#pragma unroll
        for (int nt = 0; nt < 8; ++nt) {
            const int jj = nt * 16 + lm;
#pragma unroll
            for (int r = 0; r < 4; ++r)
                Ps[(irow + r) * 136 + jj] = (f16)acc[mt][nt][r];
        }
    }
    __syncthreads();

    // ---- phase 4: O = P~ V (wave tile 32x64: 2 mt x 4 nt x 4 ksteps)
    f32x4 acc2[2][4];
#pragma unroll
    for (int mt = 0; mt < 2; ++mt)
#pragma unroll
        for (int nt = 0; nt < 4; ++nt) acc2[mt][nt] = (f32x4)0.f;
#pragma unroll
    for (int ks = 0; ks < 4; ++ks) {
        f16x8 pf[2];
#pragma unroll
        for (int mt = 0; mt < 2; ++mt)
            pf[mt] = *(const f16x8*)&Ps[(ib + mt * 16 + lm) * 136 + ks * 32 + q * 8];
#pragma unroll
        for (int nt = 0; nt < 4; ++nt) {
            f16x8 vf = *(const f16x8*)&Vt[(nt * 16 + lm) * 136 + ks * 32 + q * 8];
#pragma unroll
            for (int mt = 0; mt < 2; ++mt)
                acc2[mt][nt] = __builtin_amdgcn_mfma_f32_16x16x32_f16(
                    pf[mt], vf, acc2[mt][nt], 0, 0, 0);
        }
    }

    // ---- epilogue: apply deferred 1/sum, write f32
#pragma unroll
    for (int mt = 0; mt < 2; ++mt) {
        const int irow = ib + mt * 16 + q * 4;
#pragma unroll
        for (int nt = 0; nt < 4; ++nt) {
            const int d = nt * 16 + lm;
#pragma unroll
            for (int r = 0; r < 4; ++r)
                cout[(size_t)((irow + r) * 256 + l) * D_DIM + h * 64 + d] =
                    acc2[mt][nt][r] * inv_sum[mt][r];
        }
    }
}

// ---------------------------------------------------------------------------
extern "C" void kernel_launch(void* const* d_in, const int* in_sizes, int n_in,
                              void* d_out, int out_size, void* d_ws, size_t ws_size,
                              hipStream_t stream)
{
    const float* x     = (const float*)d_in[0];
    const float* w_row = (const float*)d_in[1];
    const float* b_row = (const float*)d_in[2];
    const float* w_col = (const float*)d_in[3];
    const float* b_col = (const float*)d_in[4];
    const float* g1    = (const float*)d_in[5];
    const float* be1   = (const float*)d_in[6];
    const float* g2    = (const float*)d_in[7];
    const float* be2   = (const float*)d_in[8];
    float* out = (float*)d_out;

    char* ws = (char*)d_ws;
    f16*   qt     = (f16*)(ws + WS_QT_OFF);
    f16*   kt     = (f16*)(ws + WS_KT_OFF);
    f16*   vt     = (f16*)(ws + WS_VT_OFF);
    f16*   p      = (f16*)(ws + WS_P_OFF);      // col phase, aliases qt/kt/vt
    float* lpart  = (float*)(ws + WS_LPART_OFF);
    f16*   pt     = (f16*)(ws + WS_PT_OFF);
    f16*   xh     = (f16*)(ws + WS_XH_OFF);     // also out1_h after step 5
    f16*   wrh    = (f16*)(ws + WS_WRH_OFF);
    f16*   wch    = (f16*)(ws + WS_WCH_OFF);
    f16*   rout_h = qt;                          // qt dead after row_logits

    // 0) f32 -> f16 converts
    cvt_f32_f16<<<NROW * D_DIM / 1024, 256, 0, stream>>>(x, xh);
    cvt_f32_f16<<<TD * D_DIM / 1024, 256, 0, stream>>>(w_row, wrh);
    cvt_f32_f16<<<TD * D_DIM / 1024, 256, 0, stream>>>(w_col, wch);
    // 1) row QKV projection (256x192 ring MFMA, best measured) -> qt/kt/vt
    mfma_gemm_row<<<dim3(12, 128), 512, 0, stream>>>(xh, wrh, b_row, qt, kt, vt);
    // 2) tied row logits (MFMA, split-K=8: 384 blocks vs 192)
    row_logits_mfma<<<dim3(2, 2, 96), 256, 0, stream>>>(qt, kt, lpart);
    // 3) softmax over j (sums 8 partials) -> f16 probs
    softmax256_8<<<H_DIM * L_DIM, 256, 0, stream>>>(lpart, pt);
    // 4) row PV (MFMA) -> rout_h f16 (qt slot; qt dead after step 2)
    row_pv_mfma<<<dim3(64, 2, H_DIM), 256, 0, stream>>>(pt, vt, rout_h);
    // 5) out1_h = f16(LN(xh + row_out))  (xh overwritten in place, row-local)
    add_ln_out16<<<NROW, 256, 0, stream>>>(xh, rout_h, g1, be1, xh);
    // 6) col QKV projection (256x192 ring MFMA) -> p (overwrites qt/kt/vt)
    mfma_gemm_qkv<<<dim3(12, 128), 512, 0, stream>>>(xh, wch, b_col, p);
    // 7) column attention (MFMA) -> d_out (scratch)
    col_attn_mfma<<<dim3(L_DIM, H_DIM), 256, 0, stream>>>(p, out);
    // 8) out = LN(out1_h + col_out), in place on d_out
    add_ln_in16<<<NROW, 256, 0, stream>>>(xh, out, g2, be2);
}

// Round 7
// 645.050 us; speedup vs baseline: 1.1774x; 1.0680x over previous
//
#include <hip/hip_runtime.h>

// Problem constants (fixed by the reference): B=1
#define S_DIM 128
#define L_DIM 256
#define D_DIM 768
#define H_DIM 12
#define TD    2304            // 3*D
#define NROW  32768           // S*L
#define KDIM  768
#define LN_EPS 1e-5f

typedef unsigned short u16;
typedef unsigned int   u32;
typedef _Float16 f16;
typedef _Float16 f16x8 __attribute__((ext_vector_type(8)));
typedef _Float16 f16x4 __attribute__((ext_vector_type(4)));
typedef float    f32x4 __attribute__((ext_vector_type(4)));

// Workspace layout (bytes), total 235,143,168 (< 255 MB proven):
//  region R (151 MB, off 0) is time-multiplexed:
//    row phase : qt f16[H][L][8192] 50.33M | kt same | vt f16[H][8192][256] 50.33M
//                (qt slot reused as rout_h f16[NROW][D] after row_logits)
//    col phase : p  f16[(l*128+s)][TD]  151 MB  (ROW-PERMUTED for col_attn
//                locality: block l reads a contiguous 590 KB window)
//  lpart  : f32 [8][H][L][L]  25,165,824   (split-K=8 partials for row logits)
//  pt     : f16 [H][L][L]      1,572,864
//  xh/u1h : f16 [NROW][D]     50,331,648
//  wr_h   : f16 [TD][D]        3,538,944
//  wc_h   : f16 [TD][D]        3,538,944
#define WS_QT_OFF     0
#define WS_KT_OFF     50331648
#define WS_VT_OFF     100663296
#define WS_P_OFF      0
#define WS_LPART_OFF  150994944
#define WS_PT_OFF     176160768
#define WS_XH_OFF     177733632
#define WS_WRH_OFF    228065280
#define WS_WCH_OFF    231604224

// fp16 staging (NOT bf16): row logits accumulate K=8192 products; bf16 failed
// absmax. fp16 passes at 0.047 with fp16-input MFMA, fp32 accum.
__device__ __forceinline__ void gload_lds16(const void* g, void* l) {
    __builtin_amdgcn_global_load_lds((const __attribute__((address_space(1))) void*)g,
                                     (__attribute__((address_space(3))) void*)l, 16, 0, 0);
}

// ---------------------------------------------------------------------------
// f32 -> f16 convert, 4 elems/thread, grid sized exactly (n % 1024 == 0).
// ---------------------------------------------------------------------------
__global__ __launch_bounds__(256)
void cvt_f32_f16(const float* __restrict__ in, f16* __restrict__ out)
{
    int i = blockIdx.x * 256 + threadIdx.x;
    float4 v = ((const float4*)in)[i];
    f16x4 o; o.x = (f16)v.x; o.y = (f16)v.y; o.z = (f16)v.z; o.w = (f16)v.w;
    ((f16x4*)out)[i] = o;
}

// ---------------------------------------------------------------------------
// MFMA GEMM core (m97 pattern, used by logits/PV): 128x128 tile, BK=32,
// 256 thr = 4 waves (2x2 of 64x64), each wave 4x4 of mfma_f32_16x16x32_f16.
// ---------------------------------------------------------------------------
#define MFMA_PROLOG(KROW)                                                     \
    __shared__ f16 As[128 * 32];                                              \
    __shared__ f16 Bs[128 * 32];                                              \
    const int tid  = threadIdx.x;                                             \
    const int lane = tid & 63;                                                \
    const int w    = tid >> 6;                                                \
    const int wr   = (w >> 1) * 64;                                           \
    const int wc   = (w & 1) * 64;                                            \
    const int lm   = lane & 15;                                               \
    const int q    = lane >> 4;                                               \
    size_t soff[2];                                                           \
    int    ldsc[2];                                                           \
    _Pragma("unroll")                                                         \
    for (int t = 0; t < 2; ++t) {                                             \
        int c  = w * 128 + t * 64 + lane;                                     \
        int m  = c >> 2;                                                      \
        int gj = (c & 3) ^ ((m >> 1) & 3);                                    \
        soff[t] = (size_t)m * (KROW) + gj * 8;                                \
        ldsc[t] = (w * 128 + t * 64) * 8;                                     \
    }                                                                         \
    int chA[4], chB[4];                                                       \
    _Pragma("unroll")                                                         \
    for (int t = 0; t < 4; ++t) {                                             \
        int ma = wr + t * 16 + lm;                                            \
        chA[t] = ma * 4 + (q ^ ((ma >> 1) & 3));                              \
        int mb = wc + t * 16 + lm;                                            \
        chB[t] = mb * 4 + (q ^ ((mb >> 1) & 3));                              \
    }                                                                         \
    f32x4 acc[4][4];                                                          \
    _Pragma("unroll")                                                         \
    for (int i = 0; i < 4; ++i)                                               \
        _Pragma("unroll")                                                     \
        for (int j = 0; j < 4; ++j) acc[i][j] = (f32x4)0.f;

#define MFMA_KLOOP(baseA, baseB, KLEN)                                        \
    for (int k0 = 0; k0 < (KLEN); k0 += 32) {                                 \
        _Pragma("unroll")                                                     \
        for (int t = 0; t < 2; ++t) {                                         \
            gload_lds16((baseA) + soff[t] + k0, &As[ldsc[t]]);                \
            gload_lds16((baseB) + soff[t] + k0, &Bs[ldsc[t]]);                \
        }                                                                     \
        __syncthreads();                                                      \
        f16x8 af[4], bf[4];                                                   \
        _Pragma("unroll")                                                     \
        for (int t = 0; t < 4; ++t) af[t] = *(const f16x8*)&As[chA[t] * 8];   \
        _Pragma("unroll")                                                     \
        for (int t = 0; t < 4; ++t) bf[t] = *(const f16x8*)&Bs[chB[t] * 8];   \
        _Pragma("unroll")                                                     \
        for (int mt = 0; mt < 4; ++mt)                                        \
            _Pragma("unroll")                                                 \
            for (int nt = 0; nt < 4; ++nt)                                    \
                acc[mt][nt] = __builtin_amdgcn_mfma_f32_16x16x32_f16(         \
                    af[mt], bf[nt], acc[mt][nt], 0, 0, 0);                    \
        __syncthreads();                                                      \
    }

// ---------------------------------------------------------------------------
// 256x192-tile GEMM core with counted-vmcnt ring (best measured: R3/R6,
// 169-172us; UNCHANGED — six schedule variants span 169-235, this is the
// floor; staging is L2-BW-bound: ~120 B/cyc/CU demand vs ~56 supply).
// ---------------------------------------------------------------------------
#define R3_WAIT_(N) asm volatile("s_waitcnt vmcnt(" #N ")" ::: "memory")
#define R3_WAIT(N)  R3_WAIT_(N)

#define R3_PROLOG()                                                           \
    __shared__ f16 As0[256 * 64];                                             \
    __shared__ f16 As1[256 * 64];                                             \
    __shared__ f16 As2[256 * 64];                                             \
    __shared__ f16 Bs0[192 * 64];                                             \
    __shared__ f16 Bs1[192 * 64];                                             \
    const int tid  = threadIdx.x;                                             \
    const int lane = tid & 63;                                                \
    const int w    = tid >> 6;                                                \
    const int wr   = (w >> 1) * 64;                                           \
    const int wc   = (w & 1) * 96;                                            \
    const int lm   = lane & 15;                                               \
    const int q    = lane >> 4;                                               \
    size_t soffA[4];                                                          \
    _Pragma("unroll")                                                         \
    for (int i = 0; i < 4; ++i) {                                             \
        int c = i * 512 + tid;                                                \
        int r = c >> 3;                                                       \
        int j = (c & 7) ^ (r & 7);                                            \
        soffA[i] = (size_t)r * KDIM + j * 8;                                  \
    }                                                                         \
    size_t soffB[3];                                                          \
    _Pragma("unroll")                                                         \
    for (int i = 0; i < 3; ++i) {                                             \
        int c = i * 512 + tid;                                                \
        int r = c >> 3;                                                       \
        int j = (c & 7) ^ (r & 7);                                            \
        soffB[i] = (size_t)r * KDIM + j * 8;                                  \
    }                                                                         \
    f32x4 acc[4][6];                                                          \
    _Pragma("unroll")                                                         \
    for (int i = 0; i < 4; ++i)                                               \
        _Pragma("unroll")                                                     \
        for (int j = 0; j < 6; ++j) acc[i][j] = (f32x4)0.f;

#define R3_STAGE_A(Ad, kk)                                                    \
    _Pragma("unroll")                                                         \
    for (int i = 0; i < 4; ++i)                                               \
        gload_lds16(baseA + soffA[i] + (size_t)(kk) * 64,                     \
                    &Ad[(i * 512 + w * 64) * 8]);

#define R3_STAGE_B(Bd, kk)                                                    \
    _Pragma("unroll")                                                         \
    for (int i = 0; i < 3; ++i)                                               \
        gload_lds16(baseB + soffB[i] + (size_t)(kk) * 64,                     \
                    &Bd[(i * 512 + w * 64) * 8]);

#define R3_FRAG(buf, row, ks)                                                 \
    (*(const f16x8*)&buf[(size_t)(row) * 64 +                                 \
                         ((((ks) * 4 + q) ^ ((row) & 7)) * 8)])

#define R3_COMPUTE(Ab, Bb)                                                    \
    _Pragma("unroll")                                                         \
    for (int ks = 0; ks < 2; ++ks) {                                          \
        f16x8 af[4], bf[6];                                                   \
        _Pragma("unroll")                                                     \
        for (int mt = 0; mt < 4; ++mt)                                        \
            af[mt] = R3_FRAG(Ab, wr + mt * 16 + lm, ks);                      \
        _Pragma("unroll")                                                     \
        for (int nt = 0; nt < 6; ++nt)                                        \
            bf[nt] = R3_FRAG(Bb, wc + nt * 16 + lm, ks);                      \
        __builtin_amdgcn_s_setprio(1);                                        \
        _Pragma("unroll")                                                     \
        for (int mt = 0; mt < 4; ++mt)                                        \
            _Pragma("unroll")                                                 \
            for (int nt = 0; nt < 6; ++nt)                                    \
                acc[mt][nt] = __builtin_amdgcn_mfma_f32_16x16x32_f16(         \
                    af[mt], bf[nt], acc[mt][nt], 0, 0, 0);                    \
        __builtin_amdgcn_s_setprio(0);                                        \
    }

#define R3_TILE(Ab, Bb, SB, Bn, kb, SA, An, ka, WN)                           \
    R3_WAIT(WN);                                                              \
    __builtin_amdgcn_s_barrier();                                             \
    __builtin_amdgcn_sched_barrier(0);                                        \
    if (SB) { R3_STAGE_B(Bn, kb) }                                            \
    if (SA) { R3_STAGE_A(An, ka) }                                            \
    R3_COMPUTE(Ab, Bb)

// KDIM=768 -> 12 tiles, fully peeled. A buf = t%3, B buf = t%2.
#define R3_KLOOP768()                                                         \
    R3_STAGE_A(As0, 0)                                                        \
    R3_STAGE_B(Bs0, 0)                                                        \
    R3_STAGE_A(As1, 1)                                                        \
    R3_TILE(As0, Bs0, 1, Bs1, 1,  1, As2, 2,  4)                              \
    R3_TILE(As1, Bs1, 1, Bs0, 2,  1, As0, 3,  4)                              \
    R3_TILE(As2, Bs0, 1, Bs1, 3,  1, As1, 4,  4)                              \
    R3_TILE(As0, Bs1, 1, Bs0, 4,  1, As2, 5,  4)                              \
    R3_TILE(As1, Bs0, 1, Bs1, 5,  1, As0, 6,  4)                              \
    R3_TILE(As2, Bs1, 1, Bs0, 6,  1, As1, 7,  4)                              \
    R3_TILE(As0, Bs0, 1, Bs1, 7,  1, As2, 8,  4)                              \
    R3_TILE(As1, Bs1, 1, Bs0, 8,  1, As0, 9,  4)                              \
    R3_TILE(As2, Bs0, 1, Bs1, 9,  1, As1, 10, 4)                              \
    R3_TILE(As0, Bs1, 1, Bs0, 10, 1, As2, 11, 4)                              \
    R3_TILE(As1, Bs0, 1, Bs1, 11, 0, As0, 0,  4)                              \
    R3_TILE(As2, Bs1, 0, Bs0, 0,  0, As0, 0,  0)

// XCD-aware bijective swizzle: nwg = 12*128 = 1536 = 8*192 (divisible).
#define R3_SWIZZLE()                                                          \
    const int wg   = blockIdx.y * 12 + blockIdx.x;                            \
    const int swz  = (wg & 7) * 192 + (wg >> 3);                              \
    const int row0 = (swz / 12) * 256;                                        \
    const int col0 = (swz % 12) * 192;

// ---------------------------------------------------------------------------
// GEMM2 (col QKV): C = A*W^T + bias -> p f16, ROW-PERMUTED: tile row n
// (= s*256+l, s fixed per tile) stored at p[(l*128+s)]. col_attn block l
// then reads rows l*128..l*128+127 = one contiguous 590 KB window.
// ---------------------------------------------------------------------------
__global__ __launch_bounds__(512, 2)
void mfma_gemm_qkv(const f16* __restrict__ A, const f16* __restrict__ W,
                   const float* __restrict__ bias, f16* __restrict__ C)
{
    R3_SWIZZLE()
    R3_PROLOG()
    const f16* baseA = A + (size_t)row0 * KDIM;
    const f16* baseB = W + (size_t)col0 * KDIM;
    R3_KLOOP768()

    // C/D layout: col=lane&15, row=quad*4+reg
    const int srow = row0 >> 8;           // s index, constant per tile
    float bv[6];
#pragma unroll
    for (int nt = 0; nt < 6; ++nt) bv[nt] = bias[col0 + wc + nt * 16 + lm];
#pragma unroll
    for (int mt = 0; mt < 4; ++mt) {
        int lrow = wr + mt * 16 + q * 4;  // = grow & 255 (row0 mult of 256)
#pragma unroll
        for (int nt = 0; nt < 6; ++nt) {
            int gcol = col0 + wc + nt * 16 + lm;
#pragma unroll
            for (int r = 0; r < 4; ++r)
                C[(size_t)((lrow + r) * 128 + srow) * TD + gcol] =
                    (f16)(acc[mt][nt][r] + bv[nt]);
        }
    }
}

// ---------------------------------------------------------------------------
// GEMM1 (row QKV): same core but scatter epilogue:
//   q -> qt[h][i][s*64+c], k -> kt[h][j][s*64+c], v -> vt[h][s*64+d][j].
// col0 tiles (192-wide) never straddle the 768/1536 q/k/v boundaries.
// ---------------------------------------------------------------------------
__global__ __launch_bounds__(512, 2)
void mfma_gemm_row(const f16* __restrict__ A, const f16* __restrict__ W,
                   const float* __restrict__ bias,
                   f16* __restrict__ qt, f16* __restrict__ kt,
                   f16* __restrict__ vt)
{
    R3_SWIZZLE()
    R3_PROLOG()
    const f16* baseA = A + (size_t)row0 * KDIM;
    const f16* baseB = W + (size_t)col0 * KDIM;
    R3_KLOOP768()

    if (col0 < 1536) {
        f16* dst = (col0 < 768) ? qt : kt;
        const int cbase = (col0 < 768) ? col0 : col0 - 768;
#pragma unroll
        for (int nt = 0; nt < 6; ++nt) {
            int gcol = cbase + wc + nt * 16 + lm;
            int h = gcol >> 6, c = gcol & 63;
            float b = bias[col0 + wc + nt * 16 + lm];
#pragma unroll
            for (int mt = 0; mt < 4; ++mt) {
                int n0 = row0 + wr + mt * 16 + q * 4;
#pragma unroll
                for (int r = 0; r < 4; ++r) {
                    int n = n0 + r;
                    int s = n >> 8, ii = n & 255;
                    dst[(((size_t)h * 256 + ii) * 128 + s) * 64 + c] =
                        (f16)(acc[mt][nt][r] + b);
                }
            }
        }
    } else {
#pragma unroll
        for (int nt = 0; nt < 6; ++nt) {
            int gcol = col0 + wc + nt * 16 + lm;
            int vcol = gcol - 1536;
            int h = vcol >> 6, d = vcol & 63;
            float b = bias[gcol];
#pragma unroll
            for (int mt = 0; mt < 4; ++mt) {
                int n0 = row0 + wr + mt * 16 + q * 4;
                int s = n0 >> 8, j0 = n0 & 255;   // r stays within one s
                f16x4 pack;
#pragma unroll
                for (int r = 0; r < 4; ++r) pack[r] = (f16)(acc[mt][nt][r] + b);
                *(f16x4*)&vt[((((size_t)h * 128 + s) * 64 + d) << 8) + j0] = pack;
            }
        }
    }
}

// ---------------------------------------------------------------------------
// Row logits via MFMA: split-K=8 partials. grid (2, 2, 96): z = h*8+sp.
// ---------------------------------------------------------------------------
__global__ __launch_bounds__(256)
void row_logits_mfma(const f16* __restrict__ qt, const f16* __restrict__ kt,
                     float* __restrict__ lpart)
{
    const int i0 = blockIdx.y * 128;
    const int j0 = blockIdx.x * 128;
    const int h  = blockIdx.z >> 3;
    const int sp = blockIdx.z & 7;
    MFMA_PROLOG(8192)
    const f16* baseA = qt + ((size_t)h * 256 + i0) * 8192 + sp * 1024;
    const f16* baseB = kt + ((size_t)h * 256 + j0) * 8192 + sp * 1024;
    MFMA_KLOOP(baseA, baseB, 1024)

    float* outp = lpart + (size_t)(sp * 12 + h) * 65536;
#pragma unroll
    for (int mt = 0; mt < 4; ++mt) {
        int grow = i0 + wr + mt * 16 + q * 4;
#pragma unroll
        for (int nt = 0; nt < 4; ++nt) {
            int gcol = j0 + wc + nt * 16 + lm;
#pragma unroll
            for (int r = 0; r < 4; ++r)
                outp[(size_t)(grow + r) * 256 + gcol] = acc[mt][nt][r];
        }
    }
}

// ---------------------------------------------------------------------------
// softmax over rows of 256, summing 8 split-K partials; probs out f16.
// Wave-per-row rewrite: 4 rows/block, float4 loads, shuffle reduce,
// ZERO barriers/LDS (was 16 barrier rounds). grid = H*L/4 = 768.
// ---------------------------------------------------------------------------
__global__ __launch_bounds__(256)
void softmax256_8(const float* __restrict__ lpart, f16* __restrict__ pt)
{
    const int row  = blockIdx.x * 4 + (threadIdx.x >> 6);
    const int lane = threadIdx.x & 63;
    const size_t idx = (size_t)row * 256 + lane * 4;
    const size_t P = (size_t)12 * 65536;
    float4 v = *(const float4*)&lpart[idx];
#pragma unroll
    for (int p8 = 1; p8 < 8; ++p8) {
        float4 u = *(const float4*)&lpart[idx + p8 * P];
        v.x += u.x; v.y += u.y; v.z += u.z; v.w += u.w;
    }
    float m = fmaxf(fmaxf(v.x, v.y), fmaxf(v.z, v.w));
#pragma unroll
    for (int d = 1; d < 64; d <<= 1) m = fmaxf(m, __shfl_xor(m, d));
    float e0 = __expf(v.x - m), e1 = __expf(v.y - m);
    float e2 = __expf(v.z - m), e3 = __expf(v.w - m);
    float s = e0 + e1 + e2 + e3;
#pragma unroll
    for (int d = 1; d < 64; d <<= 1) s += __shfl_xor(s, d);
    float inv = 1.f / s;
    f16x4 o;
    o[0] = (f16)(e0 * inv); o[1] = (f16)(e1 * inv);
    o[2] = (f16)(e2 * inv); o[3] = (f16)(e3 * inv);
    *(f16x4*)&pt[idx] = o;
}

// ---------------------------------------------------------------------------
// Row PV via MFMA: per h, out[i,(s,d)] = sum_j pt[h][i][j] * vt[h][(s,d)][j].
// Output f16 (rout_h, in the dead qt slot).
// ---------------------------------------------------------------------------
__global__ __launch_bounds__(256)
void row_pv_mfma(const f16* __restrict__ pt, const f16* __restrict__ vt,
                 f16* __restrict__ rout)
{
    const int n0t = blockIdx.x * 128;
    const int i0  = blockIdx.y * 128;
    const int h   = blockIdx.z;
    MFMA_PROLOG(256)
    const f16* baseA = pt + (size_t)h * 65536 + (size_t)i0 * 256;
    const f16* baseB = vt + ((size_t)h * 8192 + n0t) * 256;
    MFMA_KLOOP(baseA, baseB, 256)

#pragma unroll
    for (int mt = 0; mt < 4; ++mt) {
        int irow = i0 + wr + mt * 16 + q * 4;
#pragma unroll
        for (int nt = 0; nt < 4; ++nt) {
            int n = n0t + wc + nt * 16 + lm;
            int s = n >> 6, d = n & 63;
#pragma unroll
            for (int r = 0; r < 4; ++r)
                rout[(size_t)(s * 256 + irow + r) * D_DIM + h * 64 + d] =
                    (f16)acc[mt][nt][r];
        }
    }
}

// ---------------------------------------------------------------------------
// out1_h = f16(LN(x16 + r)); wave-per-row: 4 rows/block, one 64-lane wave
// per row, f16x8/f16x4 vec loads, shuffle reduce, zero barriers/LDS.
// Per lane: 8 elems at lane*8 (16B aligned) + 4 elems at 512+lane*4 (8B).
// grid = NROW/4 = 8192.
// ---------------------------------------------------------------------------
__global__ __launch_bounds__(256)
void add_ln_out16(const f16* __restrict__ x16, const f16* __restrict__ r,
                  const float* __restrict__ g, const float* __restrict__ beta,
                  f16* __restrict__ out16)
{
    const int n    = blockIdx.x * 4 + (threadIdx.x >> 6);
    const int lane = threadIdx.x & 63;
    const size_t base = (size_t)n * D_DIM;
    const int oa = lane * 8, ob = 512 + lane * 4;

    f16x8 xa = *(const f16x8*)&x16[base + oa];
    f16x8 ra = *(const f16x8*)&r[base + oa];
    f16x4 xb = *(const f16x4*)&x16[base + ob];
    f16x4 rb = *(const f16x4*)&r[base + ob];

    float va[8], vb[4]; float s = 0.f;
#pragma unroll
    for (int e = 0; e < 8; ++e) { va[e] = (float)xa[e] + (float)ra[e]; s += va[e]; }
#pragma unroll
    for (int e = 0; e < 4; ++e) { vb[e] = (float)xb[e] + (float)rb[e]; s += vb[e]; }
#pragma unroll
    for (int d = 1; d < 64; d <<= 1) s += __shfl_xor(s, d);
    float mean = s * (1.f / 768.f);
    float sq = 0.f;
#pragma unroll
    for (int e = 0; e < 8; ++e) { float dd = va[e] - mean; sq += dd * dd; }
#pragma unroll
    for (int e = 0; e < 4; ++e) { float dd = vb[e] - mean; sq += dd * dd; }
#pragma unroll
    for (int d = 1; d < 64; d <<= 1) sq += __shfl_xor(sq, d);
    float rstd = rsqrtf(sq * (1.f / 768.f) + LN_EPS);

    float4 g0 = *(const float4*)&g[oa], g1 = *(const float4*)&g[oa + 4];
    float4 b0 = *(const float4*)&beta[oa], b1 = *(const float4*)&beta[oa + 4];
    float4 g2 = *(const float4*)&g[ob], b2 = *(const float4*)&beta[ob];
    float ga[8] = {g0.x,g0.y,g0.z,g0.w,g1.x,g1.y,g1.z,g1.w};
    float ba[8] = {b0.x,b0.y,b0.z,b0.w,b1.x,b1.y,b1.z,b1.w};
    float gb[4] = {g2.x,g2.y,g2.z,g2.w};
    float bb[4] = {b2.x,b2.y,b2.z,b2.w};

    f16x8 outa; f16x4 outb;
#pragma unroll
    for (int e = 0; e < 8; ++e)
        outa[e] = (f16)((va[e] - mean) * rstd * ga[e] + ba[e]);
#pragma unroll
    for (int e = 0; e < 4; ++e)
        outb[e] = (f16)((vb[e] - mean) * rstd * gb[e] + bb[e]);
    *(f16x8*)&out16[base + oa] = outa;
    *(f16x4*)&out16[base + ob] = outb;
}

// ---------------------------------------------------------------------------
// out = LN(x16 + r) f32, in place on r. Same wave-per-row structure.
// grid = NROW/4 = 8192.
// ---------------------------------------------------------------------------
__global__ __launch_bounds__(256)
void add_ln_in16(const f16* __restrict__ x16, float* __restrict__ r,
                 const float* __restrict__ g, const float* __restrict__ beta)
{
    const int n    = blockIdx.x * 4 + (threadIdx.x >> 6);
    const int lane = threadIdx.x & 63;
    const size_t base = (size_t)n * D_DIM;
    const int oa = lane * 8, ob = 512 + lane * 4;

    f16x8 xa = *(const f16x8*)&x16[base + oa];
    float4 r0 = *(const float4*)&r[base + oa];
    float4 r1 = *(const float4*)&r[base + oa + 4];
    f16x4 xb = *(const f16x4*)&x16[base + ob];
    float4 r2 = *(const float4*)&r[base + ob];
    float rav[8] = {r0.x,r0.y,r0.z,r0.w,r1.x,r1.y,r1.z,r1.w};
    float rbv[4] = {r2.x,r2.y,r2.z,r2.w};

    float va[8], vb[4]; float s = 0.f;
#pragma unroll
    for (int e = 0; e < 8; ++e) { va[e] = (float)xa[e] + rav[e]; s += va[e]; }
#pragma unroll
    for (int e = 0; e < 4; ++e) { vb[e] = (float)xb[e] + rbv[e]; s += vb[e]; }
#pragma unroll
    for (int d = 1; d < 64; d <<= 1) s += __shfl_xor(s, d);
    float mean = s * (1.f / 768.f);
    float sq = 0.f;
#pragma unroll
    for (int e = 0; e < 8; ++e) { float dd = va[e] - mean; sq += dd * dd; }
#pragma unroll
    for (int e = 0; e < 4; ++e) { float dd = vb[e] - mean; sq += dd * dd; }
#pragma unroll
    for (int d = 1; d < 64; d <<= 1) sq += __shfl_xor(sq, d);
    float rstd = rsqrtf(sq * (1.f / 768.f) + LN_EPS);

    float4 g0 = *(const float4*)&g[oa], g1 = *(const float4*)&g[oa + 4];
    float4 b0 = *(const float4*)&beta[oa], b1 = *(const float4*)&beta[oa + 4];
    float4 g2 = *(const float4*)&g[ob], b2 = *(const float4*)&beta[ob];
    float ga[8] = {g0.x,g0.y,g0.z,g0.w,g1.x,g1.y,g1.z,g1.w};
    float ba[8] = {b0.x,b0.y,b0.z,b0.w,b1.x,b1.y,b1.z,b1.w};
    float gb[4] = {g2.x,g2.y,g2.z,g2.w};
    float bb[4] = {b2.x,b2.y,b2.z,b2.w};

    float4 o0, o1, o2;
    o0.x = (va[0]-mean)*rstd*ga[0]+ba[0]; o0.y = (va[1]-mean)*rstd*ga[1]+ba[1];
    o0.z = (va[2]-mean)*rstd*ga[2]+ba[2]; o0.w = (va[3]-mean)*rstd*ga[3]+ba[3];
    o1.x = (va[4]-mean)*rstd*ga[4]+ba[4]; o1.y = (va[5]-mean)*rstd*ga[5]+ba[5];
    o1.z = (va[6]-mean)*rstd*ga[6]+ba[6]; o1.w = (va[7]-mean)*rstd*ga[7]+ba[7];
    o2.x = (vb[0]-mean)*rstd*gb[0]+bb[0]; o2.y = (vb[1]-mean)*rstd*gb[1]+bb[1];
    o2.z = (vb[2]-mean)*rstd*gb[2]+bb[2]; o2.w = (vb[3]-mean)*rstd*gb[3]+bb[3];
    *(float4*)&r[base + oa] = o0;
    *(float4*)&r[base + oa + 4] = o1;
    *(float4*)&r[base + ob] = o2;
}

// ---------------------------------------------------------------------------
// Column attention via MFMA. One block per (l,h): grid (256, 12), 256 thr.
// p is row-permuted [(l*128+s)][TD]: block reads a contiguous 590 KB window.
// ---------------------------------------------------------------------------
__global__ __launch_bounds__(256, 3)
void col_attn_mfma(const f16* __restrict__ p, float* __restrict__ cout)
{
    __shared__ char smem[54272];
    f16* Qs = (f16*)smem;             // [128][72]
    f16* Ks = (f16*)(smem + 18432);   // [128][72]
    f16* Ps = (f16*)smem;             // [128][136] overlay (after barrier)
    f16* Vt = (f16*)(smem + 36864);   // [64][136]

    const int tid  = threadIdx.x;
    const int lane = tid & 63;
    const int w    = tid >> 6;
    const int lm   = lane & 15;
    const int q    = lane >> 4;
    const int l = blockIdx.x, h = blockIdx.y;
    const int ib = w * 32;

    // ---- phase 1: stage Q,K row-major; V transposed into Vt[d][j]
    {
        const int r  = tid >> 1;          // s index 0..127
        const int hc = (tid & 1) * 32;    // c half
        const f16* rowp = p + (size_t)(l * 128 + r) * TD + h * 64 + hc;
#pragma unroll
        for (int cc = 0; cc < 4; ++cc)
            *(float4*)&Qs[r * 72 + hc + cc * 8] = *(const float4*)(rowp + cc * 8);
#pragma unroll
        for (int cc = 0; cc < 4; ++cc)
            *(float4*)&Ks[r * 72 + hc + cc * 8] = *(const float4*)(rowp + 768 + cc * 8);
#pragma unroll
        for (int cc = 0; cc < 4; ++cc) {
            union { float4 f; u16 u[8]; } vb;
            vb.f = *(const float4*)(rowp + 1536 + cc * 8);
#pragma unroll
            for (int e = 0; e < 8; ++e) {
                int d = hc + cc * 8 + e;
                ((u16*)Vt)[d * 136 + r] = vb.u[e];
            }
        }
    }
    __syncthreads();

    // ---- phase 2: S = Q K^T (wave tile 32x128: 2 mt x 8 nt x 2 ksteps)
    f32x4 acc[2][8];
#pragma unroll
    for (int mt = 0; mt < 2; ++mt)
#pragma unroll
        for (int nt = 0; nt < 8; ++nt) acc[mt][nt] = (f32x4)0.f;
#pragma unroll
    for (int ks = 0; ks < 2; ++ks) {
        f16x8 af[2];
#pragma unroll
        for (int mt = 0; mt < 2; ++mt)
            af[mt] = *(const f16x8*)&Qs[(ib + mt * 16 + lm) * 72 + ks * 32 + q * 8];
#pragma unroll
        for (int nt = 0; nt < 8; ++nt) {
            f16x8 bf = *(const f16x8*)&Ks[(nt * 16 + lm) * 72 + ks * 32 + q * 8];
#pragma unroll
            for (int mt = 0; mt < 2; ++mt)
                acc[mt][nt] = __builtin_amdgcn_mfma_f32_16x16x32_f16(
                    af[mt], bf, acc[mt][nt], 0, 0, 0);
        }
    }
    __syncthreads();   // all Qs/Ks frag reads done before Ps overlay writes

    // ---- phase 3: softmax over j in C-layout; write exp to Ps (f16)
    float inv_sum[2][4];
#pragma unroll
    for (int mt = 0; mt < 2; ++mt) {
#pragma unroll
        for (int r = 0; r < 4; ++r) {
            float m = acc[mt][0][r];
#pragma unroll
            for (int nt = 1; nt < 8; ++nt) m = fmaxf(m, acc[mt][nt][r]);
#pragma unroll
            for (int d = 1; d < 16; d <<= 1) m = fmaxf(m, __shfl_xor(m, d));
            float s = 0.f;
#pragma unroll
            for (int nt = 0; nt < 8; ++nt) {
                float e = __expf(acc[mt][nt][r] - m);
                acc[mt][nt][r] = e; s += e;
            }
#pragma unroll
            for (int d = 1; d < 16; d <<= 1) s += __shfl_xor(s, d);
            inv_sum[mt][r] = 1.f / s;
        }
        const int irow = ib + mt * 16 + q * 4;
#pragma unroll
        for (int nt = 0; nt < 8; ++nt) {
            const int jj = nt * 16 + lm;
#pragma unroll
            for (int r = 0; r < 4; ++r)
                Ps[(irow + r) * 136 + jj] = (f16)acc[mt][nt][r];
        }
    }
    __syncthreads();

    // ---- phase 4: O = P~ V (wave tile 32x64: 2 mt x 4 nt x 4 ksteps)
    f32x4 acc2[2][4];
#pragma unroll
    for (int mt = 0; mt < 2; ++mt)
#pragma unroll
        for (int nt = 0; nt < 4; ++nt) acc2[mt][nt] = (f32x4)0.f;
#pragma unroll
    for (int ks = 0; ks < 4; ++ks) {
        f16x8 pf[2];
#pragma unroll
        for (int mt = 0; mt < 2; ++mt)
            pf[mt] = *(const f16x8*)&Ps[(ib + mt * 16 + lm) * 136 + ks * 32 + q * 8];
#pragma unroll
        for (int nt = 0; nt < 4; ++nt) {
            f16x8 vf = *(const f16x8*)&Vt[(nt * 16 + lm) * 136 + ks * 32 + q * 8];
#pragma unroll
            for (int mt = 0; mt < 2; ++mt)
                acc2[mt][nt] = __builtin_amdgcn_mfma_f32_16x16x32_f16(
                    pf[mt], vf, acc2[mt][nt], 0, 0, 0);
        }
    }

    // ---- epilogue: apply deferred 1/sum, write f32
#pragma unroll
    for (int mt = 0; mt < 2; ++mt) {
        const int irow = ib + mt * 16 + q * 4;
#pragma unroll
        for (int nt = 0; nt < 4; ++nt) {
            const int d = nt * 16 + lm;
#pragma unroll
            for (int r = 0; r < 4; ++r)
                cout[(size_t)((irow + r) * 256 + l) * D_DIM + h * 64 + d] =
                    acc2[mt][nt][r] * inv_sum[mt][r];
        }
    }
}

// ---------------------------------------------------------------------------
extern "C" void kernel_launch(void* const* d_in, const int* in_sizes, int n_in,
                              void* d_out, int out_size, void* d_ws, size_t ws_size,
                              hipStream_t stream)
{
    const float* x     = (const float*)d_in[0];
    const float* w_row = (const float*)d_in[1];
    const float* b_row = (const float*)d_in[2];
    const float* w_col = (const float*)d_in[3];
    const float* b_col = (const float*)d_in[4];
    const float* g1    = (const float*)d_in[5];
    const float* be1   = (const float*)d_in[6];
    const float* g2    = (const float*)d_in[7];
    const float* be2   = (const float*)d_in[8];
    float* out = (float*)d_out;

    char* ws = (char*)d_ws;
    f16*   qt     = (f16*)(ws + WS_QT_OFF);
    f16*   kt     = (f16*)(ws + WS_KT_OFF);
    f16*   vt     = (f16*)(ws + WS_VT_OFF);
    f16*   p      = (f16*)(ws + WS_P_OFF);      // col phase, aliases qt/kt/vt
    float* lpart  = (float*)(ws + WS_LPART_OFF);
    f16*   pt     = (f16*)(ws + WS_PT_OFF);
    f16*   xh     = (f16*)(ws + WS_XH_OFF);     // also out1_h after step 5
    f16*   wrh    = (f16*)(ws + WS_WRH_OFF);
    f16*   wch    = (f16*)(ws + WS_WCH_OFF);
    f16*   rout_h = qt;                          // qt dead after row_logits

    // 0) f32 -> f16 converts
    cvt_f32_f16<<<NROW * D_DIM / 1024, 256, 0, stream>>>(x, xh);
    cvt_f32_f16<<<TD * D_DIM / 1024, 256, 0, stream>>>(w_row, wrh);
    cvt_f32_f16<<<TD * D_DIM / 1024, 256, 0, stream>>>(w_col, wch);
    // 1) row QKV projection (256x192 ring MFMA, best measured) -> qt/kt/vt
    mfma_gemm_row<<<dim3(12, 128), 512, 0, stream>>>(xh, wrh, b_row, qt, kt, vt);
    // 2) tied row logits (MFMA, split-K=8)
    row_logits_mfma<<<dim3(2, 2, 96), 256, 0, stream>>>(qt, kt, lpart);
    // 3) softmax over j (sums 8 partials, wave-per-row) -> f16 probs
    softmax256_8<<<H_DIM * L_DIM / 4, 256, 0, stream>>>(lpart, pt);
    // 4) row PV (MFMA) -> rout_h f16 (qt slot; qt dead after step 2)
    row_pv_mfma<<<dim3(64, 2, H_DIM), 256, 0, stream>>>(pt, vt, rout_h);
    // 5) out1_h = f16(LN(xh + row_out)), wave-per-row (xh overwritten in place)
    add_ln_out16<<<NROW / 4, 256, 0, stream>>>(xh, rout_h, g1, be1, xh);
    // 6) col QKV projection (256x192 ring MFMA) -> p row-permuted [(l,s)][TD]
    mfma_gemm_qkv<<<dim3(12, 128), 512, 0, stream>>>(xh, wch, b_col, p);
    // 7) column attention (MFMA, contiguous p window) -> d_out (scratch)
    col_attn_mfma<<<dim3(L_DIM, H_DIM), 256, 0, stream>>>(p, out);
    // 8) out = LN(out1_h + col_out), wave-per-row, in place on d_out
    add_ln_in16<<<NROW / 4, 256, 0, stream>>>(xh, out, g2, be2);
}